// Round 1
// baseline (2591.730 us; speedup 1.0000x reference)
//
#include <hip/hip_runtime.h>
#include <cstddef>
#include <cstdint>

#define NN 1024
#define BB 16
#define HH 64
#define NKNOTS 11

// workspace layout (floats)
#define WT_OFF   0
#define WT_SZ    (3 * NN * NN)
#define S_OFF    (WT_OFF + WT_SZ)
#define S_SZ     (4 * NN * NN)     // ring of 4 time slices, each [NN][BB*HH]
#define Z_OFF    (S_OFF + S_SZ)
#define DINV_OFF (Z_OFF + NN)
#define LOSS_OFF (DINV_OFF + NN)

// -------------------------------------------------------------------------
// Kernel 1: per-row softmax denominator Z[j] and degree rsqrt dinv[j]
// -------------------------------------------------------------------------
__global__ __launch_bounds__(256) void rowstats_kernel(
    const float* __restrict__ emb, const float* __restrict__ A,
    float* __restrict__ Z, float* __restrict__ dinv)
{
  const int j = blockIdx.x;
  const int tid = threadIdx.x;
  __shared__ float ej[64];
  __shared__ float r1[256], r2[256];
  if (tid < 64) ej[tid] = emb[j * 64 + tid];
  __syncthreads();
  float zs = 0.f, as = 0.f;
  for (int i = tid; i < NN; i += 256) {
    const float4* er = (const float4*)(emb + (size_t)i * 64);
    float dot = 0.f;
#pragma unroll
    for (int q = 0; q < 16; ++q) {
      float4 e = er[q];
      dot += e.x * ej[q * 4 + 0] + e.y * ej[q * 4 + 1] +
             e.z * ej[q * 4 + 2] + e.w * ej[q * 4 + 3];
    }
    zs += expf(fmaxf(dot, 0.f));   // exp(relu(.)) ; softmax denom (shift-free is safe: dot is small)
    as += A[(size_t)j * NN + i];
  }
  r1[tid] = zs; r2[tid] = as;
  __syncthreads();
  for (int s = 128; s > 0; s >>= 1) {
    if (tid < s) { r1[tid] += r1[tid + s]; r2[tid] += r2[tid + s]; }
    __syncthreads();
  }
  if (tid == 0) {
    Z[j] = r1[0];
    dinv[j] = rsqrtf(r2[0] + 1.0f);   // Ah rowsum = A rowsum + 1 (diag)
  }
}

// -------------------------------------------------------------------------
// Kernel 2: WT[d][i][j] = (dsteps[j][i]==d) ? W[j][i] : 0   (transposed bins)
// -------------------------------------------------------------------------
__global__ __launch_bounds__(256) void build_wt_kernel(
    const float* __restrict__ emb, const float* __restrict__ A,
    const float* __restrict__ delay, const float* __restrict__ Z,
    const float* __restrict__ dinv, float* __restrict__ WT)
{
  const int i = blockIdx.x;
  const int tid = threadIdx.x;
  __shared__ float ei[64];
  if (tid < 64) ei[tid] = emb[i * 64 + tid];
  __syncthreads();
  const float di = dinv[i];
  for (int j = tid; j < NN; j += 256) {
    const float4* er = (const float4*)(emb + (size_t)j * 64);
    float dot = 0.f;
#pragma unroll
    for (int q = 0; q < 16; ++q) {
      float4 e = er[q];
      dot += e.x * ei[q * 4 + 0] + e.y * ei[q * 4 + 1] +
             e.z * ei[q * 4 + 2] + e.w * ei[q * 4 + 3];
    }
    float sem = expf(fmaxf(dot, 0.f)) / Z[j];
    float aji = A[(size_t)j * NN + i] + ((i == j) ? 1.f : 0.f);
    float ac = sem + dinv[j] * di * aji;
    float w = (ac > 0.001f) ? ac : 0.f;
    float dl = fminf(fmaxf(delay[(size_t)j * NN + i], 0.f), 2.f);
    int dsv = (int)rintf(dl);          // matches jnp.round (half-to-even)
    WT[(size_t)0 * (NN * NN) + (size_t)i * NN + j] = (dsv == 0) ? w : 0.f;
    WT[(size_t)1 * (NN * NN) + (size_t)i * NN + j] = (dsv == 1) ? w : 0.f;
    WT[(size_t)2 * (NN * NN) + (size_t)i * NN + j] = (dsv == 2) ? w : 0.f;
  }
}

// -------------------------------------------------------------------------
// Kernel 3: history init. S[t][n][b*64+h] = hid[b,n,t*64+h], t=0,1
//           hid = relu(x0@W1+b1)@W2+b2 , x0 = coeff_a[b,n,0,:]
// -------------------------------------------------------------------------
__global__ __launch_bounds__(128) void init_s_kernel(
    const float* __restrict__ ca, const float* __restrict__ W1,
    const float* __restrict__ b1, const float* __restrict__ W2,
    const float* __restrict__ b2, float* __restrict__ S)
{
  const int n = blockIdx.x;
  const int tid = threadIdx.x;   // 128 threads
  __shared__ float l1[64];
  for (int b = 0; b < BB; ++b) {
    size_t cbase = ((size_t)(b * NN + n) * NKNOTS + 0) * 2;
    float x0 = ca[cbase + 0];
    float x1 = ca[cbase + 1];
    if (tid < 64)
      l1[tid] = fmaxf(x0 * W1[0 * 64 + tid] + x1 * W1[1 * 64 + tid] + b1[tid], 0.f);
    __syncthreads();
    float acc = b2[tid];
#pragma unroll 8
    for (int h = 0; h < 64; ++h) acc = fmaf(l1[h], W2[h * 128 + tid], acc);
    int t = tid >> 6, hh = tid & 63;
    S[(size_t)t * (NN * NN) + (size_t)n * NN + b * 64 + hh] = acc;
    __syncthreads();
  }
}

// -------------------------------------------------------------------------
// Kernel 4: one scan step.
//  agg[i,c] = sum_d sum_j WT[d][i][j] * S[slot(max(k+1-d,0))][j][c]   (c = b*64+h)
//  pre = agg@Wm + h_k@Ws + dx@Wx + db ; h_new = tanh(pre) -> S[slot(k+2)]
//  + Huber-loss partial via reg head; + y_pred head at k==11
// -------------------------------------------------------------------------
__global__ __launch_bounds__(256) void step_kernel(
    const float* __restrict__ WT, float* __restrict__ S,
    const float* __restrict__ Wm, const float* __restrict__ Wsm,
    const float* __restrict__ Wx, const float* __restrict__ db,
    const float* __restrict__ cb, const float* __restrict__ cc,
    const float* __restrict__ cd, const float* __restrict__ ca,
    const float* __restrict__ rW1, const float* __restrict__ rb1,
    const float* __restrict__ rW2, const float* __restrict__ rb2,
    const float* __restrict__ pW1, const float* __restrict__ pb1,
    const float* __restrict__ pW2, const float* __restrict__ pb2,
    float* __restrict__ out, float* __restrict__ loss, int k)
{
  __shared__ __align__(16) float As[16][68];
  __shared__ __align__(16) float Bs[16][68];
  __shared__ __align__(16) float aggS[64][68];
  __shared__ __align__(16) float hS[64][68];
  __shared__ float sWx[128];
  __shared__ float sdb[64];
  __shared__ float redbuf[64];

  const int tid = threadIdx.x;
  const int i0 = blockIdx.x * 64;   // output-row tile
  const int b  = blockIdx.y;        // batch (= 64-col tile)
  const int c0 = b * 64;
  const int tx = tid & 15, ty = tid >> 4;

  if (tid < 128) sWx[tid] = Wx[tid];
  if (tid < 64)  sdb[tid] = db[tid];

  const int ai = tid >> 2, aj = (tid & 3) * 4;   // A-tile load map (64x16)
  const int bj = tid >> 4, bc = (tid & 15) * 4;  // B-tile load map (16x64)

  float acc[4][4];
#pragma unroll
  for (int r = 0; r < 4; ++r)
#pragma unroll
    for (int c = 0; c < 4; ++c) acc[r][c] = 0.f;

  // ---- main GEMM: K = 3 bins x 1024 ----
  for (int d = 0; d < 3; ++d) {
    int td = k + 1 - d; if (td < 0) td = 0;
    const float* Ap = WT + (size_t)d * (NN * NN) + (size_t)i0 * NN;
    const float* Bp = S + (size_t)(td & 3) * (NN * NN) + c0;
    for (int j0 = 0; j0 < NN; j0 += 16) {
      float4 av = *(const float4*)(Ap + (size_t)ai * NN + j0 + aj);
      float4 bv = *(const float4*)(Bp + (size_t)(j0 + bj) * NN + bc);
      __syncthreads();                    // protect previous iter's LDS reads
      As[aj + 0][ai] = av.x; As[aj + 1][ai] = av.y;
      As[aj + 2][ai] = av.z; As[aj + 3][ai] = av.w;
      *(float4*)&Bs[bj][bc] = bv;
      __syncthreads();
#pragma unroll
      for (int kk = 0; kk < 16; ++kk) {
        float4 a4 = *(const float4*)&As[kk][ty * 4];
        float4 b4 = *(const float4*)&Bs[kk][tx * 4];
        float avr[4] = {a4.x, a4.y, a4.z, a4.w};
        float bvr[4] = {b4.x, b4.y, b4.z, b4.w};
#pragma unroll
        for (int r = 0; r < 4; ++r)
#pragma unroll
          for (int c = 0; c < 4; ++c)
            acc[r][c] = fmaf(avr[r], bvr[c], acc[r][c]);
      }
    }
  }
  __syncthreads();

  // ---- stage agg tile and h_k tile in LDS ----
#pragma unroll
  for (int r = 0; r < 4; ++r)
#pragma unroll
    for (int c = 0; c < 4; ++c)
      aggS[ty * 4 + r][tx * 4 + c] = acc[r][c];
  {
    const float* Hp = S + (size_t)((k + 1) & 3) * (NN * NN) + c0;
#pragma unroll
    for (int rep = 0; rep < 4; ++rep) {
      int row = rep * 16 + bj;
      *(float4*)&hS[row][bc] = *(const float4*)(Hp + (size_t)(i0 + row) * NN + bc);
    }
  }
  __syncthreads();

  // ---- mini-GEMM: pre_lin = [agg | h_k] (64x128) @ [Wm;Ws] (128x64) ----
  float acc2[4][4];
#pragma unroll
  for (int r = 0; r < 4; ++r)
#pragma unroll
    for (int c = 0; c < 4; ++c) acc2[r][c] = 0.f;

  for (int j0 = 0; j0 < 128; j0 += 16) {
    const float* src = (j0 < 64) ? (Wm + j0 * 64) : (Wsm + (j0 - 64) * 64);
    float4 wv = *(const float4*)(src + bj * 64 + bc);
    __syncthreads();
    *(float4*)&Bs[bj][bc] = wv;
    __syncthreads();
    const float (*Mp)[68] = (j0 < 64) ? aggS : hS;
    const int kb = j0 & 63;
#pragma unroll
    for (int kk = 0; kk < 16; ++kk) {
      float4 b4 = *(const float4*)&Bs[kk][tx * 4];
      float bvr[4] = {b4.x, b4.y, b4.z, b4.w};
#pragma unroll
      for (int r = 0; r < 4; ++r) {
        float a = Mp[ty * 4 + r][kb + kk];
#pragma unroll
        for (int c = 0; c < 4; ++c)
          acc2[r][c] = fmaf(a, bvr[c], acc2[r][c]);
      }
    }
  }
  __syncthreads();

  // ---- dx@Wx + bias, tanh, write S[k+2] ----
  const int ksp = (k < 11) ? k : 10;
  float* Sw = S + (size_t)((k + 2) & 3) * (NN * NN) + c0;
  float hn[4][4];
#pragma unroll
  for (int r = 0; r < 4; ++r) {
    int iG = i0 + ty * 4 + r;
    size_t cbase = ((size_t)(b * NN + iG) * NKNOTS + ksp) * 2;
    float dx0 = cb[cbase + 0], dx1 = cb[cbase + 1];
    if (k == 11) {   // frac = 1: der = b + 2c + 3d
      dx0 += 2.f * cc[cbase + 0] + 3.f * cd[cbase + 0];
      dx1 += 2.f * cc[cbase + 1] + 3.f * cd[cbase + 1];
    }
#pragma unroll
    for (int c = 0; c < 4; ++c) {
      int hcol = tx * 4 + c;
      float pre = acc2[r][c] + dx0 * sWx[hcol] + dx1 * sWx[64 + hcol] + sdb[hcol];
      hn[r][c] = tanhf(pre);   // h_new = h + STEP*(tanh(pre)-h), STEP=1
    }
    float4 st = make_float4(hn[r][0], hn[r][1], hn[r][2], hn[r][3]);
    *(float4*)(Sw + (size_t)iG * NN + tx * 4) = st;
  }
  // overwrite hS with h_new for the heads
#pragma unroll
  for (int r = 0; r < 4; ++r)
#pragma unroll
    for (int c = 0; c < 4; ++c)
      hS[ty * 4 + r][tx * 4 + c] = hn[r][c];
  __syncthreads();

  // ---- reg head + Huber partial ----
  {
    const int ri = tid >> 2;
    const int mg = (tid & 3) * 8;
    float rpart = 0.f;
#pragma unroll
    for (int m = 0; m < 8; ++m) {
      int mm = mg + m;
      float s = rb1[mm];
#pragma unroll 8
      for (int h = 0; h < 64; ++h) s = fmaf(hS[ri][h], rW1[h * 32 + mm], s);
      rpart += fmaxf(s, 0.f) * rW2[mm];
    }
    rpart += __shfl_down(rpart, 1);
    rpart += __shfl_down(rpart, 2);
    if ((tid & 3) == 0) {
      float rv = rpart + rb2[0];
      int iG = i0 + ri;
      size_t tb = ((size_t)(b * NN + iG) * NKNOTS + ksp) * 2;
      float tgt = ca[tb];
      if (k == 11) tgt += cb[tb] + cc[tb] + cd[tb];   // frac=1: a+b+c+d
      float dv = rv - tgt;
      float ad = fabsf(dv);
      redbuf[ri] = (ad < 1.f) ? 0.5f * dv * dv : (ad - 0.5f);
    }
    __syncthreads();
    if (tid < 64) {
      float v = redbuf[tid];
      v += __shfl_down(v, 32);
      v += __shfl_down(v, 16);
      v += __shfl_down(v, 8);
      v += __shfl_down(v, 4);
      v += __shfl_down(v, 2);
      v += __shfl_down(v, 1);
      if (tid == 0) atomicAdd(loss, v);
    }
  }

  // ---- pred head (k == 11 only) ----
  if (k == 11) {
    __syncthreads();
    const int ri = tid >> 2;
    const int mg = (tid & 3) * 8;
#pragma unroll
    for (int m = 0; m < 8; ++m) {
      int mm = mg + m;
      float s = pb1[mm];
#pragma unroll 8
      for (int h = 0; h < 64; ++h) s = fmaf(hS[ri][h], pW1[h * 32 + mm], s);
      aggS[ri][mm] = fmaxf(s, 0.f);
    }
    __syncthreads();
#pragma unroll
    for (int rep = 0; rep < 3; ++rep) {
      int idx = tid + rep * 256;        // 768 = 64 rows x 12 outs
      int i_ = idx / 12, o = idx % 12;
      float s = pb2[o];
#pragma unroll
      for (int m = 0; m < 32; ++m) s = fmaf(aggS[i_][m], pW2[m * 12 + o], s);
      out[((size_t)b * NN + (i0 + i_)) * 12 + o] = s;
    }
  }
}

__global__ void finalize_kernel(const float* __restrict__ loss, float* __restrict__ out)
{
  out[196608] = loss[0] * (1.0f / 196608.0f);
}

// -------------------------------------------------------------------------
extern "C" void kernel_launch(void* const* d_in, const int* in_sizes, int n_in,
                              void* d_out, int out_size, void* d_ws, size_t ws_size,
                              hipStream_t stream)
{
  const float* A     = (const float*)d_in[0];
  const float* delay = (const float*)d_in[1];
  const float* ca    = (const float*)d_in[2];
  const float* cb    = (const float*)d_in[3];
  const float* cc    = (const float*)d_in[4];
  const float* cd    = (const float*)d_in[5];
  const float* emb   = (const float*)d_in[6];
  const float* iW1   = (const float*)d_in[7];
  const float* ib1   = (const float*)d_in[8];
  const float* iW2   = (const float*)d_in[9];
  const float* ib2   = (const float*)d_in[10];
  const float* Wm    = (const float*)d_in[11];
  const float* Wsm   = (const float*)d_in[12];
  const float* Wx    = (const float*)d_in[13];
  const float* db    = (const float*)d_in[14];
  const float* rW1   = (const float*)d_in[15];
  const float* rb1   = (const float*)d_in[16];
  const float* rW2   = (const float*)d_in[17];
  const float* rb2   = (const float*)d_in[18];
  const float* pW1   = (const float*)d_in[19];
  const float* pb1   = (const float*)d_in[20];
  const float* pW2   = (const float*)d_in[21];
  const float* pb2   = (const float*)d_in[22];

  float* ws   = (float*)d_ws;
  float* out  = (float*)d_out;
  float* WT   = ws + WT_OFF;
  float* S    = ws + S_OFF;
  float* Z    = ws + Z_OFF;
  float* dinv = ws + DINV_OFF;
  float* loss = ws + LOSS_OFF;

  hipMemsetAsync(loss, 0, sizeof(float), stream);
  rowstats_kernel<<<NN, 256, 0, stream>>>(emb, A, Z, dinv);
  build_wt_kernel<<<NN, 256, 0, stream>>>(emb, A, delay, Z, dinv, WT);
  init_s_kernel<<<NN, 128, 0, stream>>>(ca, iW1, ib1, iW2, ib2, S);
  for (int k = 0; k < 12; ++k) {
    step_kernel<<<dim3(16, 16), 256, 0, stream>>>(
        WT, S, Wm, Wsm, Wx, db, cb, cc, cd, ca,
        rW1, rb1, rW2, rb2, pW1, pb1, pW2, pb2, out, loss, k);
  }
  finalize_kernel<<<1, 1, 0, stream>>>(loss, out);
}

// Round 2
// 991.010 us; speedup vs baseline: 2.6152x; 2.6152x over previous
//
#include <hip/hip_runtime.h>
#include <cstddef>
#include <cstdint>

#define NN 1024
#define BB 16
#define NKNOTS 11

typedef __attribute__((ext_vector_type(8))) short short8_v;
typedef __attribute__((ext_vector_type(4))) float f32x4;
typedef __attribute__((ext_vector_type(8))) unsigned short ushort8_v;

// ---- workspace byte offsets ----
#define WTHI_OFF  ((size_t)0)
#define WTLO_OFF  ((size_t)6 << 20)    // 3*1M ushort = 6 MB each
#define STHI_OFF  ((size_t)12 << 20)   // 4*1M ushort = 8 MB each
#define STLO_OFF  ((size_t)20 << 20)
#define LOSS_OFF  ((size_t)28 << 20)
#define Z_OFF     (((size_t)28 << 20) + 64)
#define DINV_OFF  (((size_t)28 << 20) + 64 + 4096)

__device__ __forceinline__ unsigned short f2bf(float x) {
  unsigned int u = __float_as_uint(x);
  return (unsigned short)((u + 0x7FFFu + ((u >> 16) & 1u)) >> 16);
}
__device__ __forceinline__ float bf2f(unsigned short h) {
  return __uint_as_float(((unsigned int)h) << 16);
}
__device__ __forceinline__ void gload16(const void* g, void* l) {
  __builtin_amdgcn_global_load_lds(
      (const __attribute__((address_space(1))) unsigned int*)g,
      (__attribute__((address_space(3))) unsigned int*)l, 16, 0, 0);
}

// -------------------------------------------------------------------------
// Kernel 1: per-row softmax denominator Z[j] and degree rsqrt dinv[j]
// -------------------------------------------------------------------------
__global__ __launch_bounds__(256) void rowstats_kernel(
    const float* __restrict__ emb, const float* __restrict__ A,
    float* __restrict__ Z, float* __restrict__ dinv)
{
  const int j = blockIdx.x;
  const int tid = threadIdx.x;
  __shared__ float ej[64];
  __shared__ float r1[256], r2[256];
  if (tid < 64) ej[tid] = emb[j * 64 + tid];
  __syncthreads();
  float zs = 0.f, as = 0.f;
  for (int i = tid; i < NN; i += 256) {
    const float4* er = (const float4*)(emb + (size_t)i * 64);
    float dot = 0.f;
#pragma unroll
    for (int q = 0; q < 16; ++q) {
      float4 e = er[q];
      dot += e.x * ej[q * 4 + 0] + e.y * ej[q * 4 + 1] +
             e.z * ej[q * 4 + 2] + e.w * ej[q * 4 + 3];
    }
    zs += expf(fmaxf(dot, 0.f));
    as += A[(size_t)j * NN + i];
  }
  r1[tid] = zs; r2[tid] = as;
  __syncthreads();
  for (int s = 128; s > 0; s >>= 1) {
    if (tid < s) { r1[tid] += r1[tid + s]; r2[tid] += r2[tid + s]; }
    __syncthreads();
  }
  if (tid == 0) {
    Z[j] = r1[0];
    dinv[j] = rsqrtf(r2[0] + 1.0f);
  }
}

// -------------------------------------------------------------------------
// Kernel 2: WT[d][i][j] = (dsteps[j][i]==d) ? W[j][i] : 0, split bf16 hi/lo
// -------------------------------------------------------------------------
__global__ __launch_bounds__(256) void build_wt_kernel(
    const float* __restrict__ emb, const float* __restrict__ A,
    const float* __restrict__ delay, const float* __restrict__ Z,
    const float* __restrict__ dinv,
    unsigned short* __restrict__ WThi, unsigned short* __restrict__ WTlo)
{
  const int i = blockIdx.x;
  const int tid = threadIdx.x;
  __shared__ float ei[64];
  if (tid < 64) ei[tid] = emb[i * 64 + tid];
  __syncthreads();
  const float di = dinv[i];
  for (int j = tid; j < NN; j += 256) {
    const float4* er = (const float4*)(emb + (size_t)j * 64);
    float dot = 0.f;
#pragma unroll
    for (int q = 0; q < 16; ++q) {
      float4 e = er[q];
      dot += e.x * ei[q * 4 + 0] + e.y * ei[q * 4 + 1] +
             e.z * ei[q * 4 + 2] + e.w * ei[q * 4 + 3];
    }
    float sem = expf(fmaxf(dot, 0.f)) / Z[j];
    float aji = A[(size_t)j * NN + i] + ((i == j) ? 1.f : 0.f);
    float ac = sem + dinv[j] * di * aji;
    float w = (ac > 0.001f) ? ac : 0.f;
    float dl = fminf(fmaxf(delay[(size_t)j * NN + i], 0.f), 2.f);
    int dsv = (int)rintf(dl);
#pragma unroll
    for (int d0 = 0; d0 < 3; ++d0) {
      float v = (dsv == d0) ? w : 0.f;
      unsigned short hv = f2bf(v);
      size_t off = ((size_t)d0 << 20) + (size_t)i * NN + j;
      WThi[off] = hv;
      WTlo[off] = f2bf(v - bf2f(hv));
    }
  }
}

// -------------------------------------------------------------------------
// Kernel 3: history init -> transposed bf16 hi/lo ST slices 0,1
// -------------------------------------------------------------------------
__global__ __launch_bounds__(128) void init_s_kernel(
    const float* __restrict__ ca, const float* __restrict__ W1,
    const float* __restrict__ b1, const float* __restrict__ W2,
    const float* __restrict__ b2,
    unsigned short* __restrict__ SThi, unsigned short* __restrict__ STlo)
{
  const int n = blockIdx.x;
  const int tid = threadIdx.x;   // 128 threads
  __shared__ float l1[64];
  for (int b = 0; b < BB; ++b) {
    size_t cbase = ((size_t)(b * NN + n) * NKNOTS + 0) * 2;
    float x0 = ca[cbase + 0];
    float x1 = ca[cbase + 1];
    if (tid < 64)
      l1[tid] = fmaxf(x0 * W1[0 * 64 + tid] + x1 * W1[1 * 64 + tid] + b1[tid], 0.f);
    __syncthreads();
    float acc = b2[tid];
#pragma unroll 8
    for (int h = 0; h < 64; ++h) acc = fmaf(l1[h], W2[h * 128 + tid], acc);
    int t = tid >> 6, hh = tid & 63;
    size_t off = ((size_t)t << 20) + (size_t)(b * 64 + hh) * NN + n;
    unsigned short hv = f2bf(acc);
    SThi[off] = hv;
    STlo[off] = f2bf(acc - bf2f(hv));
    __syncthreads();
  }
}

// -------------------------------------------------------------------------
// Kernel 4: one scan step. MFMA bf16 hi/lo-split main GEMM + fp32 epilogue.
//  Block: 64(i) x 64(c) tile; 4 waves each own 32x32 (2x2 frags 16x16x32).
// -------------------------------------------------------------------------
__global__ __launch_bounds__(256, 1) void step_kernel(
    const unsigned short* __restrict__ WThi, const unsigned short* __restrict__ WTlo,
    unsigned short* __restrict__ SThi, unsigned short* __restrict__ STlo,
    const float* __restrict__ Wm, const float* __restrict__ Wsm,
    const float* __restrict__ Wx, const float* __restrict__ db,
    const float* __restrict__ cb, const float* __restrict__ cc,
    const float* __restrict__ cd, const float* __restrict__ ca,
    const float* __restrict__ rW1, const float* __restrict__ rb1,
    const float* __restrict__ rW2, const float* __restrict__ rb2,
    const float* __restrict__ pW1, const float* __restrict__ pb1,
    const float* __restrict__ pW2, const float* __restrict__ pb2,
    float* __restrict__ out, float* __restrict__ loss, int k)
{
  // region [0,32768): 4 staged tiles (Ahi,Alo,Bhi,Blo) 8KB each (GEMM phase)
  // region [0,17408): aggS fp32 [64][68]   (epilogue)
  // region [17408,34816): hS fp32 [64][68] (epilogue)
  // region [34816,39168): Bs fp32 [16][68] (epilogue)
  __shared__ __align__(16) char smem[39168];
  __shared__ float sWx[128];
  __shared__ float sdb[64];
  __shared__ float redbuf[64];

  const int tid = threadIdx.x;
  const int i0 = blockIdx.x * 64;
  const int b  = blockIdx.y;
  const int c0 = b * 64;
  const int lane = tid & 63;
  const int w = tid >> 6;          // wave id 0..3
  const int wr = w >> 1, wc = w & 1;

  if (tid < 128) sWx[tid] = Wx[tid];
  else if (tid < 192) sdb[tid - 128] = db[tid - 128];

  // staging map: wave w stages tile w (0=Ahi,1=Alo,2=Bhi,3=Blo)
  const int srow = lane >> 3;                 // 0..7 within 8-row group
  const int scx  = (lane & 7) ^ (srow & 7);   // swizzled 16B-chunk index
  // fragment map (16x16x32): row = lane&15, k-off = (lane>>4)*8
  const int g = lane >> 4, l15 = lane & 15;
  const int x7 = (lane & 7) << 4;
  const int kx0 = (16 * g) ^ x7;
  const int kx1 = (64 + 16 * g) ^ x7;
  const int rA = (wr * 32 + l15) * 128;
  const int rB = (wc * 32 + l15) * 128;

  f32x4 acc[2][2];
#pragma unroll
  for (int fr = 0; fr < 2; ++fr)
#pragma unroll
    for (int fc = 0; fc < 2; ++fc)
      acc[fr][fc] = (f32x4){0.f, 0.f, 0.f, 0.f};

  // ---- main GEMM: 3 bins x 1024, bf16 split (hh + hl + lh) ----
  for (int d = 0; d < 3; ++d) {
    int td = k + 1 - d; if (td < 0) td = 0;
    const unsigned short* gbase;
    if (w == 0)      gbase = WThi + ((size_t)d << 20) + (size_t)i0 * NN;
    else if (w == 1) gbase = WTlo + ((size_t)d << 20) + (size_t)i0 * NN;
    else if (w == 2) gbase = SThi + ((size_t)(td & 3) << 20) + (size_t)c0 * NN;
    else             gbase = STlo + ((size_t)(td & 3) << 20) + (size_t)c0 * NN;
    const unsigned short* gl = gbase + (size_t)srow * NN + 8 * scx;
    char* lds_w = smem + w * 8192;

    for (int j0 = 0; j0 < NN; j0 += 64) {
      __syncthreads();                 // previous iter's frag reads done
#pragma unroll
      for (int it = 0; it < 8; ++it)
        gload16(gl + j0 + (size_t)it * (8 * NN), lds_w + it * 1024);
      __syncthreads();                 // vmcnt(0) drain + barrier

      const char* tAh = smem;
      const char* tAl = smem + 8192;
      const char* tBh = smem + 16384;
      const char* tBl = smem + 24576;
#pragma unroll
      for (int ks = 0; ks < 2; ++ks) {
        const int kx = ks ? kx1 : kx0;
        short8_v ah0 = *(const short8_v*)(tAh + rA + kx);
        short8_v ah1 = *(const short8_v*)(tAh + rA + 2048 + kx);
        short8_v bh0 = *(const short8_v*)(tBh + rB + kx);
        short8_v bh1 = *(const short8_v*)(tBh + rB + 2048 + kx);
        acc[0][0] = __builtin_amdgcn_mfma_f32_16x16x32_bf16(ah0, bh0, acc[0][0], 0, 0, 0);
        acc[0][1] = __builtin_amdgcn_mfma_f32_16x16x32_bf16(ah0, bh1, acc[0][1], 0, 0, 0);
        acc[1][0] = __builtin_amdgcn_mfma_f32_16x16x32_bf16(ah1, bh0, acc[1][0], 0, 0, 0);
        acc[1][1] = __builtin_amdgcn_mfma_f32_16x16x32_bf16(ah1, bh1, acc[1][1], 0, 0, 0);
        short8_v bl0 = *(const short8_v*)(tBl + rB + kx);
        short8_v bl1 = *(const short8_v*)(tBl + rB + 2048 + kx);
        acc[0][0] = __builtin_amdgcn_mfma_f32_16x16x32_bf16(ah0, bl0, acc[0][0], 0, 0, 0);
        acc[0][1] = __builtin_amdgcn_mfma_f32_16x16x32_bf16(ah0, bl1, acc[0][1], 0, 0, 0);
        acc[1][0] = __builtin_amdgcn_mfma_f32_16x16x32_bf16(ah1, bl0, acc[1][0], 0, 0, 0);
        acc[1][1] = __builtin_amdgcn_mfma_f32_16x16x32_bf16(ah1, bl1, acc[1][1], 0, 0, 0);
        short8_v al0 = *(const short8_v*)(tAl + rA + kx);
        short8_v al1 = *(const short8_v*)(tAl + rA + 2048 + kx);
        acc[0][0] = __builtin_amdgcn_mfma_f32_16x16x32_bf16(al0, bh0, acc[0][0], 0, 0, 0);
        acc[0][1] = __builtin_amdgcn_mfma_f32_16x16x32_bf16(al0, bh1, acc[0][1], 0, 0, 0);
        acc[1][0] = __builtin_amdgcn_mfma_f32_16x16x32_bf16(al1, bh0, acc[1][0], 0, 0, 0);
        acc[1][1] = __builtin_amdgcn_mfma_f32_16x16x32_bf16(al1, bh1, acc[1][1], 0, 0, 0);
      }
    }
  }
  __syncthreads();   // frag reads done; LDS reusable

  float (*aggS)[68] = (float (*)[68])smem;
  float (*hS)[68]   = (float (*)[68])(smem + 17408);
  float (*Bs)[68]   = (float (*)[68])(smem + 34816);

  // ---- spill MFMA accumulators to aggS (C/D layout: col=lane&15, row=g*4+r)
#pragma unroll
  for (int fr = 0; fr < 2; ++fr)
#pragma unroll
    for (int fc = 0; fc < 2; ++fc)
#pragma unroll
      for (int r = 0; r < 4; ++r)
        aggS[wr * 32 + fr * 16 + g * 4 + r][wc * 32 + fc * 16 + l15] = acc[fr][fc][r];

  // ---- stage h_k tile (reconstruct fp32 = hi + lo from transposed ST) ----
  {
    const int cl = tid >> 2, ich = (tid & 3) * 16;
    size_t off = ((size_t)((k + 1) & 3) << 20) + (size_t)(c0 + cl) * NN + (i0 + ich);
    ushort8_v h0 = *(const ushort8_v*)(SThi + off);
    ushort8_v h1 = *(const ushort8_v*)(SThi + off + 8);
    ushort8_v l0 = *(const ushort8_v*)(STlo + off);
    ushort8_v l1 = *(const ushort8_v*)(STlo + off + 8);
#pragma unroll
    for (int q = 0; q < 8; ++q) {
      hS[ich + q][cl]     = bf2f(h0[q]) + bf2f(l0[q]);
      hS[ich + 8 + q][cl] = bf2f(h1[q]) + bf2f(l1[q]);
    }
  }

  // ---- mini-GEMM: pre_lin = [agg | h_k] (64x128) @ [Wm;Ws] (128x64) ----
  const int tx = tid & 15, ty = tid >> 4;
  const int bj = tid >> 4, bc = (tid & 15) * 4;
  float acc2[4][4];
#pragma unroll
  for (int r = 0; r < 4; ++r)
#pragma unroll
    for (int c = 0; c < 4; ++c) acc2[r][c] = 0.f;

  for (int j0 = 0; j0 < 128; j0 += 16) {
    const float* src = (j0 < 64) ? (Wm + j0 * 64) : (Wsm + (j0 - 64) * 64);
    float4 wv = *(const float4*)(src + bj * 64 + bc);
    __syncthreads();
    *(float4*)&Bs[bj][bc] = wv;
    __syncthreads();
    const float (*Mp)[68] = (j0 < 64) ? aggS : hS;
    const int kb = j0 & 63;
#pragma unroll
    for (int kk = 0; kk < 16; ++kk) {
      float4 b4 = *(const float4*)&Bs[kk][tx * 4];
      float bvr[4] = {b4.x, b4.y, b4.z, b4.w};
#pragma unroll
      for (int r = 0; r < 4; ++r) {
        float a = Mp[ty * 4 + r][kb + kk];
#pragma unroll
        for (int c = 0; c < 4; ++c)
          acc2[r][c] = fmaf(a, bvr[c], acc2[r][c]);
      }
    }
  }
  __syncthreads();

  // ---- dx@Wx + bias, tanh ----
  const int ksp = (k < 11) ? k : 10;
  float hn[4][4];
#pragma unroll
  for (int r = 0; r < 4; ++r) {
    int iG = i0 + ty * 4 + r;
    size_t cbase = ((size_t)(b * NN + iG) * NKNOTS + ksp) * 2;
    float dx0 = cb[cbase + 0], dx1 = cb[cbase + 1];
    if (k == 11) {   // frac = 1: der = b + 2c + 3d
      dx0 += 2.f * cc[cbase + 0] + 3.f * cd[cbase + 0];
      dx1 += 2.f * cc[cbase + 1] + 3.f * cd[cbase + 1];
    }
#pragma unroll
    for (int c = 0; c < 4; ++c) {
      int hcol = tx * 4 + c;
      float pre = acc2[r][c] + dx0 * sWx[hcol] + dx1 * sWx[64 + hcol] + sdb[hcol];
      hn[r][c] = tanhf(pre);   // h_new (STEP=1)
    }
  }
  // overwrite hS with h_new for heads + ST writeout
#pragma unroll
  for (int r = 0; r < 4; ++r)
#pragma unroll
    for (int c = 0; c < 4; ++c)
      hS[ty * 4 + r][tx * 4 + c] = hn[r][c];
  __syncthreads();

  // ---- write h_new to transposed bf16 hi/lo ring slice (k+2)&3 ----
  {
    const int cl = tid >> 2, ich = (tid & 3) * 16;
    size_t off = ((size_t)((k + 2) & 3) << 20) + (size_t)(c0 + cl) * NN + (i0 + ich);
    ushort8_v H0, H1, L0, L1;
#pragma unroll
    for (int q = 0; q < 8; ++q) {
      float v0 = hS[ich + q][cl];
      unsigned short hh0 = f2bf(v0);
      H0[q] = hh0; L0[q] = f2bf(v0 - bf2f(hh0));
      float v1 = hS[ich + 8 + q][cl];
      unsigned short hh1 = f2bf(v1);
      H1[q] = hh1; L1[q] = f2bf(v1 - bf2f(hh1));
    }
    *(ushort8_v*)(SThi + off)     = H0;
    *(ushort8_v*)(SThi + off + 8) = H1;
    *(ushort8_v*)(STlo + off)     = L0;
    *(ushort8_v*)(STlo + off + 8) = L1;
  }

  // ---- reg head + Huber partial ----
  {
    const int ri = tid >> 2;
    const int mg = (tid & 3) * 8;
    float rpart = 0.f;
#pragma unroll
    for (int m = 0; m < 8; ++m) {
      int mm = mg + m;
      float s = rb1[mm];
#pragma unroll 8
      for (int h = 0; h < 64; ++h) s = fmaf(hS[ri][h], rW1[h * 32 + mm], s);
      rpart += fmaxf(s, 0.f) * rW2[mm];
    }
    rpart += __shfl_down(rpart, 1);
    rpart += __shfl_down(rpart, 2);
    if ((tid & 3) == 0) {
      float rv = rpart + rb2[0];
      int iG = i0 + ri;
      size_t tb = ((size_t)(b * NN + iG) * NKNOTS + ksp) * 2;
      float tgt = ca[tb];
      if (k == 11) tgt += cb[tb] + cc[tb] + cd[tb];   // frac=1: a+b+c+d
      float dv = rv - tgt;
      float ad = fabsf(dv);
      redbuf[ri] = (ad < 1.f) ? 0.5f * dv * dv : (ad - 0.5f);
    }
    __syncthreads();
    if (tid < 64) {
      float v = redbuf[tid];
      v += __shfl_down(v, 32);
      v += __shfl_down(v, 16);
      v += __shfl_down(v, 8);
      v += __shfl_down(v, 4);
      v += __shfl_down(v, 2);
      v += __shfl_down(v, 1);
      if (tid == 0) atomicAdd(loss, v);
    }
  }

  // ---- pred head (k == 11 only) ----
  if (k == 11) {
    __syncthreads();
    const int ri = tid >> 2;
    const int mg = (tid & 3) * 8;
#pragma unroll
    for (int m = 0; m < 8; ++m) {
      int mm = mg + m;
      float s = pb1[mm];
#pragma unroll 8
      for (int h = 0; h < 64; ++h) s = fmaf(hS[ri][h], pW1[h * 32 + mm], s);
      aggS[ri][mm] = fmaxf(s, 0.f);
    }
    __syncthreads();
#pragma unroll
    for (int rep = 0; rep < 3; ++rep) {
      int idx = tid + rep * 256;        // 768 = 64 rows x 12 outs
      int i_ = idx / 12, o = idx % 12;
      float s = pb2[o];
#pragma unroll
      for (int m = 0; m < 32; ++m) s = fmaf(aggS[i_][m], pW2[m * 12 + o], s);
      out[((size_t)b * NN + (i0 + i_)) * 12 + o] = s;
    }
  }
}

__global__ void finalize_kernel(const float* __restrict__ loss, float* __restrict__ out)
{
  out[196608] = loss[0] * (1.0f / 196608.0f);
}

// -------------------------------------------------------------------------
extern "C" void kernel_launch(void* const* d_in, const int* in_sizes, int n_in,
                              void* d_out, int out_size, void* d_ws, size_t ws_size,
                              hipStream_t stream)
{
  const float* A     = (const float*)d_in[0];
  const float* delay = (const float*)d_in[1];
  const float* ca    = (const float*)d_in[2];
  const float* cb    = (const float*)d_in[3];
  const float* cc    = (const float*)d_in[4];
  const float* cd    = (const float*)d_in[5];
  const float* emb   = (const float*)d_in[6];
  const float* iW1   = (const float*)d_in[7];
  const float* ib1   = (const float*)d_in[8];
  const float* iW2   = (const float*)d_in[9];
  const float* ib2   = (const float*)d_in[10];
  const float* Wm    = (const float*)d_in[11];
  const float* Wsm   = (const float*)d_in[12];
  const float* Wx    = (const float*)d_in[13];
  const float* db    = (const float*)d_in[14];
  const float* rW1   = (const float*)d_in[15];
  const float* rb1   = (const float*)d_in[16];
  const float* rW2   = (const float*)d_in[17];
  const float* rb2   = (const float*)d_in[18];
  const float* pW1   = (const float*)d_in[19];
  const float* pb1   = (const float*)d_in[20];
  const float* pW2   = (const float*)d_in[21];
  const float* pb2   = (const float*)d_in[22];

  char* wsb = (char*)d_ws;
  float* out = (float*)d_out;
  unsigned short* WThi = (unsigned short*)(wsb + WTHI_OFF);
  unsigned short* WTlo = (unsigned short*)(wsb + WTLO_OFF);
  unsigned short* SThi = (unsigned short*)(wsb + STHI_OFF);
  unsigned short* STlo = (unsigned short*)(wsb + STLO_OFF);
  float* loss = (float*)(wsb + LOSS_OFF);
  float* Z    = (float*)(wsb + Z_OFF);
  float* dinv = (float*)(wsb + DINV_OFF);

  hipMemsetAsync(loss, 0, sizeof(float), stream);
  rowstats_kernel<<<NN, 256, 0, stream>>>(emb, A, Z, dinv);
  build_wt_kernel<<<NN, 256, 0, stream>>>(emb, A, delay, Z, dinv, WThi, WTlo);
  init_s_kernel<<<NN, 128, 0, stream>>>(ca, iW1, ib1, iW2, ib2, SThi, STlo);
  for (int k = 0; k < 12; ++k) {
    step_kernel<<<dim3(16, 16), 256, 0, stream>>>(
        WThi, WTlo, SThi, STlo, Wm, Wsm, Wx, db, cb, cc, cd, ca,
        rW1, rb1, rW2, rb2, pW1, pb1, pW2, pb2, out, loss, k);
  }
  finalize_kernel<<<1, 1, 0, stream>>>(loss, out);
}

// Round 3
// 948.909 us; speedup vs baseline: 2.7313x; 1.0444x over previous
//
#include <hip/hip_runtime.h>
#include <cstddef>
#include <cstdint>

#define NN 1024
#define BB 16
#define NKNOTS 11

typedef __attribute__((ext_vector_type(8))) short short8_v;
typedef __attribute__((ext_vector_type(4))) float f32x4;
typedef __attribute__((ext_vector_type(8))) unsigned short ushort8_v;

// ---- workspace byte offsets ----
#define WTHI_OFF  ((size_t)0)
#define WTLO_OFF  ((size_t)6 << 20)    // 3*1M ushort = 6 MB each
#define STHI_OFF  ((size_t)12 << 20)   // 4*1M ushort = 8 MB each
#define STLO_OFF  ((size_t)20 << 20)
#define LOSS_OFF  ((size_t)28 << 20)
#define Z_OFF     (((size_t)28 << 20) + 64)
#define DINV_OFF  (((size_t)28 << 20) + 64 + 4096)

__device__ __forceinline__ unsigned short f2bf(float x) {
  unsigned int u = __float_as_uint(x);
  return (unsigned short)((u + 0x7FFFu + ((u >> 16) & 1u)) >> 16);
}
__device__ __forceinline__ float bf2f(unsigned short h) {
  return __uint_as_float(((unsigned int)h) << 16);
}
__device__ __forceinline__ void gload16(const void* g, void* l) {
  __builtin_amdgcn_global_load_lds(
      (const __attribute__((address_space(1))) unsigned int*)g,
      (__attribute__((address_space(3))) unsigned int*)l, 16, 0, 0);
}

// -------------------------------------------------------------------------
// Kernel 1: per-row softmax denominator Z[j] and degree rsqrt dinv[j]
// -------------------------------------------------------------------------
__global__ __launch_bounds__(256) void rowstats_kernel(
    const float* __restrict__ emb, const float* __restrict__ A,
    float* __restrict__ Z, float* __restrict__ dinv)
{
  const int j = blockIdx.x;
  const int tid = threadIdx.x;
  __shared__ float ej[64];
  __shared__ float r1[256], r2[256];
  if (tid < 64) ej[tid] = emb[j * 64 + tid];
  __syncthreads();
  float zs = 0.f, as = 0.f;
  for (int i = tid; i < NN; i += 256) {
    const float4* er = (const float4*)(emb + (size_t)i * 64);
    float dot = 0.f;
#pragma unroll
    for (int q = 0; q < 16; ++q) {
      float4 e = er[q];
      dot += e.x * ej[q * 4 + 0] + e.y * ej[q * 4 + 1] +
             e.z * ej[q * 4 + 2] + e.w * ej[q * 4 + 3];
    }
    zs += expf(fmaxf(dot, 0.f));
    as += A[(size_t)j * NN + i];
  }
  r1[tid] = zs; r2[tid] = as;
  __syncthreads();
  for (int s = 128; s > 0; s >>= 1) {
    if (tid < s) { r1[tid] += r1[tid + s]; r2[tid] += r2[tid + s]; }
    __syncthreads();
  }
  if (tid == 0) {
    Z[j] = r1[0];
    dinv[j] = rsqrtf(r2[0] + 1.0f);
  }
}

// -------------------------------------------------------------------------
// Kernel 2: WT[d][i][j] = (dsteps[j][i]==d) ? W[j][i] : 0, split bf16 hi/lo
// -------------------------------------------------------------------------
__global__ __launch_bounds__(256) void build_wt_kernel(
    const float* __restrict__ emb, const float* __restrict__ A,
    const float* __restrict__ delay, const float* __restrict__ Z,
    const float* __restrict__ dinv,
    unsigned short* __restrict__ WThi, unsigned short* __restrict__ WTlo)
{
  const int i = blockIdx.x;
  const int tid = threadIdx.x;
  __shared__ float ei[64];
  if (tid < 64) ei[tid] = emb[i * 64 + tid];
  __syncthreads();
  const float di = dinv[i];
  for (int j = tid; j < NN; j += 256) {
    const float4* er = (const float4*)(emb + (size_t)j * 64);
    float dot = 0.f;
#pragma unroll
    for (int q = 0; q < 16; ++q) {
      float4 e = er[q];
      dot += e.x * ei[q * 4 + 0] + e.y * ei[q * 4 + 1] +
             e.z * ei[q * 4 + 2] + e.w * ei[q * 4 + 3];
    }
    float sem = expf(fmaxf(dot, 0.f)) / Z[j];
    float aji = A[(size_t)j * NN + i] + ((i == j) ? 1.f : 0.f);
    float ac = sem + dinv[j] * di * aji;
    float w = (ac > 0.001f) ? ac : 0.f;
    float dl = fminf(fmaxf(delay[(size_t)j * NN + i], 0.f), 2.f);
    int dsv = (int)rintf(dl);
#pragma unroll
    for (int d0 = 0; d0 < 3; ++d0) {
      float v = (dsv == d0) ? w : 0.f;
      unsigned short hv = f2bf(v);
      size_t off = ((size_t)d0 << 20) + (size_t)i * NN + j;
      WThi[off] = hv;
      WTlo[off] = f2bf(v - bf2f(hv));
    }
  }
}

// -------------------------------------------------------------------------
// Kernel 3: history init -> transposed bf16 hi/lo ST slices 0,1
// -------------------------------------------------------------------------
__global__ __launch_bounds__(128) void init_s_kernel(
    const float* __restrict__ ca, const float* __restrict__ W1,
    const float* __restrict__ b1, const float* __restrict__ W2,
    const float* __restrict__ b2,
    unsigned short* __restrict__ SThi, unsigned short* __restrict__ STlo)
{
  const int n = blockIdx.x;
  const int tid = threadIdx.x;
  __shared__ float l1[64];
  for (int b = 0; b < BB; ++b) {
    size_t cbase = ((size_t)(b * NN + n) * NKNOTS + 0) * 2;
    float x0 = ca[cbase + 0];
    float x1 = ca[cbase + 1];
    if (tid < 64)
      l1[tid] = fmaxf(x0 * W1[0 * 64 + tid] + x1 * W1[1 * 64 + tid] + b1[tid], 0.f);
    __syncthreads();
    float acc = b2[tid];
#pragma unroll 8
    for (int h = 0; h < 64; ++h) acc = fmaf(l1[h], W2[h * 128 + tid], acc);
    int t = tid >> 6, hh = tid & 63;
    size_t off = ((size_t)t << 20) + (size_t)(b * 64 + hh) * NN + n;
    unsigned short hv = f2bf(acc);
    SThi[off] = hv;
    STlo[off] = f2bf(acc - bf2f(hv));
    __syncthreads();
  }
}

// -------------------------------------------------------------------------
// Kernel 4: one scan step. Double-buffered counted-vmcnt MFMA pipeline.
//  512 threads, 8 waves = 2(wr) x 2(wc) x 2(kh K-split). Tile 64i x 64c.
// -------------------------------------------------------------------------
__global__ __launch_bounds__(512, 1) void step_kernel(
    const unsigned short* __restrict__ WThi, const unsigned short* __restrict__ WTlo,
    unsigned short* __restrict__ SThi, unsigned short* __restrict__ STlo,
    const float* __restrict__ Wm, const float* __restrict__ Wsm,
    const float* __restrict__ Wx, const float* __restrict__ db,
    const float* __restrict__ cb, const float* __restrict__ cc,
    const float* __restrict__ cd, const float* __restrict__ ca,
    const float* __restrict__ rW1, const float* __restrict__ rb1,
    const float* __restrict__ rW2, const float* __restrict__ rb2,
    const float* __restrict__ pW1, const float* __restrict__ pb1,
    const float* __restrict__ pW2, const float* __restrict__ pb2,
    float* __restrict__ out, float* __restrict__ loss, int k)
{
  // [0,32768) buf0, [32768,65536) buf1 during GEMM.
  // Each buf: [A_hi 8K][A_lo 8K][B_hi 8K][B_lo 8K]; rows 128B, XOR-chunk swizzle.
  // Epilogue overlay: aggS[64][68] @0, hS[64][68] @17408, Bs[16][68] @34816.
  __shared__ __align__(16) char smem[65536];
  __shared__ float sWx[128];
  __shared__ float sdb[64];
  __shared__ float redbuf[64];

  const int tid  = threadIdx.x;
  const int lane = tid & 63;
  const int w    = tid >> 6;            // wave 0..7
  const int bid  = blockIdx.x;
  // XCD-aware decode: xcd owns 4 i-tiles x 8 b-tiles
  const int xcd = bid & 7, qq = bid >> 3;
  const int i0 = ((xcd & 3) * 4 + (qq & 3)) * 64;
  const int b  = (xcd >> 2) * 8 + (qq >> 2);
  const int c0 = b * 64;

  const int wr = (w >> 1) & 1, wc = w & 1, kh = w >> 2;
  const int g = lane >> 4, l15 = lane & 15;

  if (tid < 128) sWx[tid] = Wx[tid];
  else if (tid < 192) sdb[tid - 128] = db[tid - 128];

  // staging role: region = w>>1 (0 Ahi,1 Alo,2 Bhi,3 Blo), half = w&1
  const int region = w >> 1;
  const int stg_row = ((w & 1) << 5) + (lane >> 3);          // local row 0..63
  const int stg_cc  = (lane & 7) ^ (stg_row & 7);            // pre-swizzled chunk
  const size_t stg_src_off = (size_t)stg_row * NN + stg_cc * 8;
  const int stg_dst = (w << 12) + (lane << 4);

  // fragment byte offsets within a 32KB buffer
  const int kch  = (((kh << 2) + g) ^ (l15 & 7)) << 4;
  const int offA0 = ((wr * 32 + l15) * 128) + kch;
  const int offA1 = offA0 + 2048;
  const int offB0 = ((wc * 32 + l15) * 128) + kch;
  const int offB1 = offB0 + 2048;

  f32x4 acc[2][2];
#pragma unroll
  for (int fr = 0; fr < 2; ++fr)
#pragma unroll
    for (int fc = 0; fc < 2; ++fc)
      acc[fr][fc] = (f32x4){0.f, 0.f, 0.f, 0.f};

  auto do_stage = [&](int t, int nb) {
    const int d  = t >> 4;
    const int jj = (t & 15) << 6;
    const unsigned short* gb;
    if (region < 2) {
      gb = (region == 0 ? WThi : WTlo) + (((size_t)d) << 20) + (size_t)i0 * NN;
    } else {
      int td = k + 1 - d; if (td < 0) td = 0;
      gb = (region == 2 ? SThi : STlo) + (((size_t)(td & 3)) << 20) + (size_t)c0 * NN;
    }
    const unsigned short* src = gb + stg_src_off + jj;
    char* dst = smem + (nb << 15) + stg_dst;
#pragma unroll
    for (int it = 0; it < 4; ++it)
      gload16(src + (size_t)it * (8 * NN), dst + (it << 10));
  };

  do_stage(0, 0);
  for (int t = 0; t < 48; ++t) {
    if (t < 47) {
      do_stage(t + 1, (t + 1) & 1);
      asm volatile("s_waitcnt vmcnt(4)" ::: "memory");   // wait current buf only
    } else {
      asm volatile("s_waitcnt vmcnt(0)" ::: "memory");
    }
    __builtin_amdgcn_s_barrier();

    const char* bp = smem + ((t & 1) << 15);
    short8_v ah0 = *(const short8_v*)(bp + offA0);
    short8_v ah1 = *(const short8_v*)(bp + offA1);
    short8_v bh0 = *(const short8_v*)(bp + 16384 + offB0);
    short8_v bh1 = *(const short8_v*)(bp + 16384 + offB1);
    short8_v al0 = *(const short8_v*)(bp + 8192 + offA0);
    short8_v al1 = *(const short8_v*)(bp + 8192 + offA1);
    short8_v bl0 = *(const short8_v*)(bp + 24576 + offB0);
    short8_v bl1 = *(const short8_v*)(bp + 24576 + offB1);
    acc[0][0] = __builtin_amdgcn_mfma_f32_16x16x32_bf16(ah0, bh0, acc[0][0], 0, 0, 0);
    acc[0][1] = __builtin_amdgcn_mfma_f32_16x16x32_bf16(ah0, bh1, acc[0][1], 0, 0, 0);
    acc[1][0] = __builtin_amdgcn_mfma_f32_16x16x32_bf16(ah1, bh0, acc[1][0], 0, 0, 0);
    acc[1][1] = __builtin_amdgcn_mfma_f32_16x16x32_bf16(ah1, bh1, acc[1][1], 0, 0, 0);
    acc[0][0] = __builtin_amdgcn_mfma_f32_16x16x32_bf16(ah0, bl0, acc[0][0], 0, 0, 0);
    acc[0][1] = __builtin_amdgcn_mfma_f32_16x16x32_bf16(ah0, bl1, acc[0][1], 0, 0, 0);
    acc[1][0] = __builtin_amdgcn_mfma_f32_16x16x32_bf16(ah1, bl0, acc[1][0], 0, 0, 0);
    acc[1][1] = __builtin_amdgcn_mfma_f32_16x16x32_bf16(ah1, bl1, acc[1][1], 0, 0, 0);
    acc[0][0] = __builtin_amdgcn_mfma_f32_16x16x32_bf16(al0, bh0, acc[0][0], 0, 0, 0);
    acc[0][1] = __builtin_amdgcn_mfma_f32_16x16x32_bf16(al0, bh1, acc[0][1], 0, 0, 0);
    acc[1][0] = __builtin_amdgcn_mfma_f32_16x16x32_bf16(al1, bh0, acc[1][0], 0, 0, 0);
    acc[1][1] = __builtin_amdgcn_mfma_f32_16x16x32_bf16(al1, bh1, acc[1][1], 0, 0, 0);
    __builtin_amdgcn_sched_barrier(0);   // keep reads/MFMAs inside the phase
    __builtin_amdgcn_s_barrier();
  }

  float (*aggS)[68] = (float (*)[68])smem;
  float (*hS)[68]   = (float (*)[68])(smem + 17408);
  float (*Bs)[68]   = (float (*)[68])(smem + 34816);

  // ---- merge kh halves: kh=0 stores, kh=1 adds ----
  if (kh == 0) {
#pragma unroll
    for (int fr = 0; fr < 2; ++fr)
#pragma unroll
      for (int fc = 0; fc < 2; ++fc)
#pragma unroll
        for (int r = 0; r < 4; ++r)
          aggS[wr * 32 + fr * 16 + g * 4 + r][wc * 32 + fc * 16 + l15] = acc[fr][fc][r];
  }
  __syncthreads();
  if (kh == 1) {
#pragma unroll
    for (int fr = 0; fr < 2; ++fr)
#pragma unroll
      for (int fc = 0; fc < 2; ++fc)
#pragma unroll
        for (int r = 0; r < 4; ++r)
          aggS[wr * 32 + fr * 16 + g * 4 + r][wc * 32 + fc * 16 + l15] += acc[fr][fc][r];
  }
  __syncthreads();

  // ---- stage h_k tile (fp32 = hi + lo from transposed ST) ----
  {
    const int cl = tid >> 3, ich = (tid & 7) * 8;
    size_t off = ((size_t)((k + 1) & 3) << 20) + (size_t)(c0 + cl) * NN + (i0 + ich);
    ushort8_v h0 = *(const ushort8_v*)(SThi + off);
    ushort8_v l0 = *(const ushort8_v*)(STlo + off);
#pragma unroll
    for (int q = 0; q < 8; ++q)
      hS[ich + q][cl] = bf2f(h0[q]) + bf2f(l0[q]);
  }
  __syncthreads();

  // ---- mini-GEMM: pre_lin = [agg | h_k] (64x128) @ [Wm;Ws] (128x64) ----
  const int tx = tid & 15;
  const int tyy = tid >> 4;            // 0..31, two rows each
  float acc2[2][4];
#pragma unroll
  for (int r = 0; r < 2; ++r)
#pragma unroll
    for (int c = 0; c < 4; ++c) acc2[r][c] = 0.f;

  for (int j0m = 0; j0m < 128; j0m += 16) {
    float4 wv;
    int bj = tid >> 4, bc = (tid & 15) * 4;
    if (tid < 256) {
      const float* src = (j0m < 64) ? (Wm + (j0m + bj) * 64) : (Wsm + (j0m - 64 + bj) * 64);
      wv = *(const float4*)(src + bc);
    }
    __syncthreads();
    if (tid < 256) *(float4*)&Bs[bj][bc] = wv;
    __syncthreads();
    const float (*Mp)[68] = (j0m < 64) ? aggS : hS;
    const int kb = j0m & 63;
#pragma unroll
    for (int kk = 0; kk < 16; ++kk) {
      float4 b4 = *(const float4*)&Bs[kk][tx * 4];
      float a0 = Mp[tyy * 2 + 0][kb + kk];
      float a1 = Mp[tyy * 2 + 1][kb + kk];
      acc2[0][0] = fmaf(a0, b4.x, acc2[0][0]); acc2[0][1] = fmaf(a0, b4.y, acc2[0][1]);
      acc2[0][2] = fmaf(a0, b4.z, acc2[0][2]); acc2[0][3] = fmaf(a0, b4.w, acc2[0][3]);
      acc2[1][0] = fmaf(a1, b4.x, acc2[1][0]); acc2[1][1] = fmaf(a1, b4.y, acc2[1][1]);
      acc2[1][2] = fmaf(a1, b4.z, acc2[1][2]); acc2[1][3] = fmaf(a1, b4.w, acc2[1][3]);
    }
  }
  __syncthreads();   // done reading aggS/hS

  // ---- dx@Wx + bias, tanh, store h_new into hS ----
  const int ksp = (k < 11) ? k : 10;
#pragma unroll
  for (int r = 0; r < 2; ++r) {
    int iG = i0 + tyy * 2 + r;
    size_t cbase = ((size_t)(b * NN + iG) * NKNOTS + ksp) * 2;
    float dx0 = cb[cbase + 0], dx1 = cb[cbase + 1];
    if (k == 11) {   // frac = 1: der = b + 2c + 3d
      dx0 += 2.f * cc[cbase + 0] + 3.f * cd[cbase + 0];
      dx1 += 2.f * cc[cbase + 1] + 3.f * cd[cbase + 1];
    }
#pragma unroll
    for (int c = 0; c < 4; ++c) {
      int hcol = tx * 4 + c;
      float pre = acc2[r][c] + dx0 * sWx[hcol] + dx1 * sWx[64 + hcol] + sdb[hcol];
      hS[tyy * 2 + r][hcol] = tanhf(pre);   // h_new (STEP=1)
    }
  }
  __syncthreads();

  // ---- write h_new to transposed bf16 hi/lo ring slice (k+2)&3 ----
  {
    const int cl = tid >> 3, ich = (tid & 7) * 8;
    size_t off = ((size_t)((k + 2) & 3) << 20) + (size_t)(c0 + cl) * NN + (i0 + ich);
    ushort8_v H, L;
#pragma unroll
    for (int q = 0; q < 8; ++q) {
      float v = hS[ich + q][cl];
      unsigned short hv = f2bf(v);
      H[q] = hv; L[q] = f2bf(v - bf2f(hv));
    }
    *(ushort8_v*)(SThi + off) = H;
    *(ushort8_v*)(STlo + off) = L;
  }

  // ---- reg head + Huber partial ----
  {
    const int ri = tid >> 3;           // row 0..63
    const int mg = (tid & 7) * 4;      // 4 mids each
    float rpart = 0.f;
#pragma unroll
    for (int m = 0; m < 4; ++m) {
      int mm = mg + m;
      float s = rb1[mm];
#pragma unroll 8
      for (int h = 0; h < 64; ++h) s = fmaf(hS[ri][h], rW1[h * 32 + mm], s);
      rpart += fmaxf(s, 0.f) * rW2[mm];
    }
    rpart += __shfl_down(rpart, 4);
    rpart += __shfl_down(rpart, 2);
    rpart += __shfl_down(rpart, 1);
    if ((tid & 7) == 0) {
      float rv = rpart + rb2[0];
      int iG = i0 + ri;
      size_t tb = ((size_t)(b * NN + iG) * NKNOTS + ksp) * 2;
      float tgt = ca[tb];
      if (k == 11) tgt += cb[tb] + cc[tb] + cd[tb];   // frac=1: a+b+c+d
      float dv = rv - tgt;
      float ad = fabsf(dv);
      redbuf[ri] = (ad < 1.f) ? 0.5f * dv * dv : (ad - 0.5f);
    }
    __syncthreads();
    if (tid < 64) {
      float v = redbuf[tid];
      v += __shfl_down(v, 32);
      v += __shfl_down(v, 16);
      v += __shfl_down(v, 8);
      v += __shfl_down(v, 4);
      v += __shfl_down(v, 2);
      v += __shfl_down(v, 1);
      if (tid == 0) atomicAdd(loss, v);
    }
  }

  // ---- pred head (k == 11 only) ----
  if (k == 11) {
    __syncthreads();
    const int ri = tid >> 3;
    const int mg = (tid & 7) * 4;
#pragma unroll
    for (int m = 0; m < 4; ++m) {
      int mm = mg + m;
      float s = pb1[mm];
#pragma unroll 8
      for (int h = 0; h < 64; ++h) s = fmaf(hS[ri][h], pW1[h * 32 + mm], s);
      aggS[ri][mm] = fmaxf(s, 0.f);
    }
    __syncthreads();
#pragma unroll
    for (int rep = 0; rep < 2; ++rep) {
      int idx = tid + rep * 512;        // 768 = 64 rows x 12 outs
      if (idx < 768) {
        int i_ = idx / 12, o = idx % 12;
        float s = pb2[o];
#pragma unroll
        for (int m = 0; m < 32; ++m) s = fmaf(aggS[i_][m], pW2[m * 12 + o], s);
        out[((size_t)b * NN + (i0 + i_)) * 12 + o] = s;
      }
    }
  }
}

__global__ void finalize_kernel(const float* __restrict__ loss, float* __restrict__ out)
{
  out[196608] = loss[0] * (1.0f / 196608.0f);
}

// -------------------------------------------------------------------------
extern "C" void kernel_launch(void* const* d_in, const int* in_sizes, int n_in,
                              void* d_out, int out_size, void* d_ws, size_t ws_size,
                              hipStream_t stream)
{
  const float* A     = (const float*)d_in[0];
  const float* delay = (const float*)d_in[1];
  const float* ca    = (const float*)d_in[2];
  const float* cb    = (const float*)d_in[3];
  const float* cc    = (const float*)d_in[4];
  const float* cd    = (const float*)d_in[5];
  const float* emb   = (const float*)d_in[6];
  const float* iW1   = (const float*)d_in[7];
  const float* ib1   = (const float*)d_in[8];
  const float* iW2   = (const float*)d_in[9];
  const float* ib2   = (const float*)d_in[10];
  const float* Wm    = (const float*)d_in[11];
  const float* Wsm   = (const float*)d_in[12];
  const float* Wx    = (const float*)d_in[13];
  const float* db    = (const float*)d_in[14];
  const float* rW1   = (const float*)d_in[15];
  const float* rb1   = (const float*)d_in[16];
  const float* rW2   = (const float*)d_in[17];
  const float* rb2   = (const float*)d_in[18];
  const float* pW1   = (const float*)d_in[19];
  const float* pb1   = (const float*)d_in[20];
  const float* pW2   = (const float*)d_in[21];
  const float* pb2   = (const float*)d_in[22];

  char* wsb = (char*)d_ws;
  float* out = (float*)d_out;
  unsigned short* WThi = (unsigned short*)(wsb + WTHI_OFF);
  unsigned short* WTlo = (unsigned short*)(wsb + WTLO_OFF);
  unsigned short* SThi = (unsigned short*)(wsb + STHI_OFF);
  unsigned short* STlo = (unsigned short*)(wsb + STLO_OFF);
  float* loss = (float*)(wsb + LOSS_OFF);
  float* Z    = (float*)(wsb + Z_OFF);
  float* dinv = (float*)(wsb + DINV_OFF);

  hipMemsetAsync(loss, 0, sizeof(float), stream);
  rowstats_kernel<<<NN, 256, 0, stream>>>(emb, A, Z, dinv);
  build_wt_kernel<<<NN, 256, 0, stream>>>(emb, A, delay, Z, dinv, WThi, WTlo);
  init_s_kernel<<<NN, 128, 0, stream>>>(ca, iW1, ib1, iW2, ib2, SThi, STlo);
  for (int k = 0; k < 12; ++k) {
    step_kernel<<<256, 512, 0, stream>>>(
        WThi, WTlo, SThi, STlo, Wm, Wsm, Wx, db, cb, cc, cd, ca,
        rW1, rb1, rW2, rb2, pW1, pb1, pW2, pb2, out, loss, k);
  }
  finalize_kernel<<<1, 1, 0, stream>>>(loss, out);
}

// Round 4
// 794.626 us; speedup vs baseline: 3.2616x; 1.1942x over previous
//
#include <hip/hip_runtime.h>
#include <cstddef>
#include <cstdint>

#define NN 1024
#define BB 16
#define NKNOTS 11

typedef __attribute__((ext_vector_type(8))) short short8_v;
typedef __attribute__((ext_vector_type(4))) float f32x4;
typedef __attribute__((ext_vector_type(8))) unsigned short ushort8_v;

// ---- workspace byte offsets ----
#define WTHI_OFF  ((size_t)0)
#define STHI_OFF  ((size_t)12 << 20)
#define STLO_OFF  ((size_t)20 << 20)
#define LOSS_OFF  ((size_t)28 << 20)
#define Z_OFF     (((size_t)28 << 20) + 64)
#define DINV_OFF  (((size_t)28 << 20) + 64 + 4096)

__device__ __forceinline__ unsigned short f2bf(float x) {
  unsigned int u = __float_as_uint(x);
  return (unsigned short)((u + 0x7FFFu + ((u >> 16) & 1u)) >> 16);
}
__device__ __forceinline__ float bf2f(unsigned short h) {
  return __uint_as_float(((unsigned int)h) << 16);
}
__device__ __forceinline__ void gload16(const void* g, void* l) {
  __builtin_amdgcn_global_load_lds(
      (const __attribute__((address_space(1))) unsigned int*)g,
      (__attribute__((address_space(3))) unsigned int*)l, 16, 0, 0);
}

// -------------------------------------------------------------------------
// Kernel 1: per-row softmax denominator Z[j] and degree rsqrt dinv[j]
// -------------------------------------------------------------------------
__global__ __launch_bounds__(256) void rowstats_kernel(
    const float* __restrict__ emb, const float* __restrict__ A,
    float* __restrict__ Z, float* __restrict__ dinv)
{
  const int j = blockIdx.x;
  const int tid = threadIdx.x;
  __shared__ float ej[64];
  __shared__ float r1[256], r2[256];
  if (tid < 64) ej[tid] = emb[j * 64 + tid];
  __syncthreads();
  float zs = 0.f, as = 0.f;
  for (int i = tid; i < NN; i += 256) {
    const float4* er = (const float4*)(emb + (size_t)i * 64);
    float dot = 0.f;
#pragma unroll
    for (int q = 0; q < 16; ++q) {
      float4 e = er[q];
      dot += e.x * ej[q * 4 + 0] + e.y * ej[q * 4 + 1] +
             e.z * ej[q * 4 + 2] + e.w * ej[q * 4 + 3];
    }
    zs += expf(fmaxf(dot, 0.f));
    as += A[(size_t)j * NN + i];
  }
  r1[tid] = zs; r2[tid] = as;
  __syncthreads();
  for (int s = 128; s > 0; s >>= 1) {
    if (tid < s) { r1[tid] += r1[tid + s]; r2[tid] += r2[tid + s]; }
    __syncthreads();
  }
  if (tid == 0) {
    Z[j] = r1[0];
    dinv[j] = rsqrtf(r2[0] + 1.0f);
  }
}

// -------------------------------------------------------------------------
// Kernel 2: WT[d][i][j] = (dsteps[j][i]==d) ? W[j][i] : 0, bf16 (single)
// -------------------------------------------------------------------------
__global__ __launch_bounds__(256) void build_wt_kernel(
    const float* __restrict__ emb, const float* __restrict__ A,
    const float* __restrict__ delay, const float* __restrict__ Z,
    const float* __restrict__ dinv, unsigned short* __restrict__ WThi)
{
  const int i = blockIdx.x;
  const int tid = threadIdx.x;
  __shared__ float ei[64];
  if (tid < 64) ei[tid] = emb[i * 64 + tid];
  __syncthreads();
  const float di = dinv[i];
  for (int j = tid; j < NN; j += 256) {
    const float4* er = (const float4*)(emb + (size_t)j * 64);
    float dot = 0.f;
#pragma unroll
    for (int q = 0; q < 16; ++q) {
      float4 e = er[q];
      dot += e.x * ei[q * 4 + 0] + e.y * ei[q * 4 + 1] +
             e.z * ei[q * 4 + 2] + e.w * ei[q * 4 + 3];
    }
    float sem = expf(fmaxf(dot, 0.f)) / Z[j];
    float aji = A[(size_t)j * NN + i] + ((i == j) ? 1.f : 0.f);
    float ac = sem + dinv[j] * di * aji;
    float w = (ac > 0.001f) ? ac : 0.f;
    float dl = fminf(fmaxf(delay[(size_t)j * NN + i], 0.f), 2.f);
    int dsv = (int)rintf(dl);
#pragma unroll
    for (int d0 = 0; d0 < 3; ++d0) {
      float v = (dsv == d0) ? w : 0.f;
      WThi[((size_t)d0 << 20) + (size_t)i * NN + j] = f2bf(v);
    }
  }
}

// -------------------------------------------------------------------------
// Kernel 3: history init -> transposed bf16 hi/lo ST slices 0,1
// -------------------------------------------------------------------------
__global__ __launch_bounds__(128) void init_s_kernel(
    const float* __restrict__ ca, const float* __restrict__ W1,
    const float* __restrict__ b1, const float* __restrict__ W2,
    const float* __restrict__ b2,
    unsigned short* __restrict__ SThi, unsigned short* __restrict__ STlo)
{
  const int n = blockIdx.x;
  const int tid = threadIdx.x;
  __shared__ float l1[64];
  for (int b = 0; b < BB; ++b) {
    size_t cbase = ((size_t)(b * NN + n) * NKNOTS + 0) * 2;
    float x0 = ca[cbase + 0];
    float x1 = ca[cbase + 1];
    if (tid < 64)
      l1[tid] = fmaxf(x0 * W1[0 * 64 + tid] + x1 * W1[1 * 64 + tid] + b1[tid], 0.f);
    __syncthreads();
    float acc = b2[tid];
#pragma unroll 8
    for (int h = 0; h < 64; ++h) acc = fmaf(l1[h], W2[h * 128 + tid], acc);
    int t = tid >> 6, hh = tid & 63;
    size_t off = ((size_t)t << 20) + (size_t)(b * 64 + hh) * NN + n;
    unsigned short hv = f2bf(acc);
    SThi[off] = hv;
    STlo[off] = f2bf(acc - bf2f(hv));
    __syncthreads();
  }
}

// -------------------------------------------------------------------------
// Kernel 4: one scan step. Single-bf16 GEMM, 4-buf 3-deep counted-vmcnt.
//  512 threads, 8 waves = 2(wr) x 2(wc) x 2(kh). Tile 64i x 64c, K=3x1024.
// -------------------------------------------------------------------------
__global__ __launch_bounds__(512, 1) void step_kernel(
    const unsigned short* __restrict__ WThi,
    unsigned short* __restrict__ SThi, unsigned short* __restrict__ STlo,
    const float* __restrict__ Wm, const float* __restrict__ Wsm,
    const float* __restrict__ Wx, const float* __restrict__ db,
    const float* __restrict__ cb, const float* __restrict__ cc,
    const float* __restrict__ cd, const float* __restrict__ ca,
    const float* __restrict__ rW1, const float* __restrict__ rb1,
    const float* __restrict__ rW2, const float* __restrict__ rb2,
    const float* __restrict__ pW1, const float* __restrict__ pb1,
    const float* __restrict__ pW2, const float* __restrict__ pb2,
    float* __restrict__ out, float* __restrict__ loss, int k)
{
  // GEMM phase: 4 buffers x 16KB: [A 8K][B 8K], rows 128B, XOR-chunk swizzle.
  // Epilogue overlay: aggS[64][68] @0, hS[64][68] @17408, Bs[16][68] @34816.
  __shared__ __align__(16) char smem[65536];
  __shared__ float sWx[128];
  __shared__ float sdb[64];
  __shared__ float redbuf[64];

  const int tid  = threadIdx.x;
  const int lane = tid & 63;
  const int w    = tid >> 6;            // wave 0..7
  const int bid  = blockIdx.x;
  // XCD-aware decode: xcd owns 4 i-tiles x 8 b-tiles (WS ~4.5MB ~ L2)
  const int xcd = bid & 7, qq = bid >> 3;
  const int i0 = ((xcd & 3) * 4 + (qq & 3)) * 64;
  const int b  = (xcd >> 2) * 8 + (qq >> 2);
  const int c0 = b * 64;

  const int wr = (w >> 1) & 1, wc = w & 1, kh = w >> 2;
  const int g = lane >> 4, l15 = lane & 15;

  if (tid < 128) sWx[tid] = Wx[tid];
  else if (tid < 192) sdb[tid - 128] = db[tid - 128];

  // staging map: each thread loads one 16B A chunk + one 16B B chunk per stage
  const int sr = (w << 3) + (lane >> 3);          // row 0..63
  const int sc = ((lane & 7) ^ (sr & 7)) << 3;    // pre-swizzled elem offset
  const size_t ssrc = (size_t)sr * NN + sc;
  const int sdst = (w << 10) + (lane << 4);       // linear LDS dest

  // fragment byte offsets (row&7 == l15&7 for all frag rows)
  const int kch   = ((((kh << 2) + g) ^ (l15 & 7)) << 4);
  const int offA0 = (wr * 32 + l15) * 128 + kch;
  const int offA1 = offA0 + 16 * 128;
  const int offB0 = 8192 + (wc * 32 + l15) * 128 + kch;
  const int offB1 = offB0 + 16 * 128;

  f32x4 acc[2][2];
#pragma unroll
  for (int fr = 0; fr < 2; ++fr)
#pragma unroll
    for (int fc = 0; fc < 2; ++fc)
      acc[fr][fc] = (f32x4){0.f, 0.f, 0.f, 0.f};

  auto do_stage = [&](int t) {
    const int d  = t >> 4;
    const int jj = (t & 15) << 6;
    int td = k + 1 - d; if (td < 0) td = 0;
    const unsigned short* As = WThi + (((size_t)d) << 20) + (size_t)i0 * NN + ssrc + jj;
    const unsigned short* Bsrc = SThi + (((size_t)(td & 3)) << 20) + (size_t)c0 * NN + ssrc + jj;
    char* dst = smem + ((t & 3) << 14) + sdst;
    gload16(As, dst);
    gload16(Bsrc, dst + 8192);
  };

  do_stage(0); do_stage(1); do_stage(2);
  for (int t = 0; t < 48; ++t) {
    if (t < 45) {
      do_stage(t + 3);
      asm volatile("s_waitcnt vmcnt(6)" ::: "memory");   // oldest stage done
    } else if (t == 45) {
      asm volatile("s_waitcnt vmcnt(4)" ::: "memory");
    } else if (t == 46) {
      asm volatile("s_waitcnt vmcnt(2)" ::: "memory");
    } else {
      asm volatile("s_waitcnt vmcnt(0)" ::: "memory");
    }
    __builtin_amdgcn_s_barrier();

    const char* bp = smem + ((t & 3) << 14);
    short8_v a0 = *(const short8_v*)(bp + offA0);
    short8_v a1 = *(const short8_v*)(bp + offA1);
    short8_v b0 = *(const short8_v*)(bp + offB0);
    short8_v b1 = *(const short8_v*)(bp + offB1);
    acc[0][0] = __builtin_amdgcn_mfma_f32_16x16x32_bf16(a0, b0, acc[0][0], 0, 0, 0);
    acc[0][1] = __builtin_amdgcn_mfma_f32_16x16x32_bf16(a0, b1, acc[0][1], 0, 0, 0);
    acc[1][0] = __builtin_amdgcn_mfma_f32_16x16x32_bf16(a1, b0, acc[1][0], 0, 0, 0);
    acc[1][1] = __builtin_amdgcn_mfma_f32_16x16x32_bf16(a1, b1, acc[1][1], 0, 0, 0);
    __builtin_amdgcn_sched_barrier(0);   // keep reads/MFMAs inside the phase
    __builtin_amdgcn_s_barrier();
  }

  float (*aggS)[68] = (float (*)[68])smem;
  float (*hS)[68]   = (float (*)[68])(smem + 17408);
  float (*Bs)[68]   = (float (*)[68])(smem + 34816);

  // ---- merge kh halves: kh=0 stores, kh=1 adds ----
  if (kh == 0) {
#pragma unroll
    for (int fr = 0; fr < 2; ++fr)
#pragma unroll
      for (int fc = 0; fc < 2; ++fc)
#pragma unroll
        for (int r = 0; r < 4; ++r)
          aggS[wr * 32 + fr * 16 + g * 4 + r][wc * 32 + fc * 16 + l15] = acc[fr][fc][r];
  }
  __syncthreads();
  if (kh == 1) {
#pragma unroll
    for (int fr = 0; fr < 2; ++fr)
#pragma unroll
      for (int fc = 0; fc < 2; ++fc)
#pragma unroll
        for (int r = 0; r < 4; ++r)
          aggS[wr * 32 + fr * 16 + g * 4 + r][wc * 32 + fc * 16 + l15] += acc[fr][fc][r];
  }
  __syncthreads();

  // ---- stage h_k tile (fp32 = hi + lo from transposed ST) ----
  {
    const int cl = tid >> 3, ich = (tid & 7) * 8;
    size_t off = ((size_t)((k + 1) & 3) << 20) + (size_t)(c0 + cl) * NN + (i0 + ich);
    ushort8_v h0 = *(const ushort8_v*)(SThi + off);
    ushort8_v l0 = *(const ushort8_v*)(STlo + off);
#pragma unroll
    for (int q = 0; q < 8; ++q)
      hS[ich + q][cl] = bf2f(h0[q]) + bf2f(l0[q]);
  }
  __syncthreads();

  // ---- mini-GEMM: pre_lin = [agg | h_k] (64x128) @ [Wm;Ws] (128x64) ----
  const int tx = tid & 15;
  const int tyy = tid >> 4;            // 0..31, two rows each
  float acc2[2][4];
#pragma unroll
  for (int r = 0; r < 2; ++r)
#pragma unroll
    for (int c = 0; c < 4; ++c) acc2[r][c] = 0.f;

  for (int j0m = 0; j0m < 128; j0m += 16) {
    float4 wv;
    int bj = tid >> 4, bc = (tid & 15) * 4;
    if (tid < 256) {
      const float* src = (j0m < 64) ? (Wm + (j0m + bj) * 64) : (Wsm + (j0m - 64 + bj) * 64);
      wv = *(const float4*)(src + bc);
    }
    __syncthreads();
    if (tid < 256) *(float4*)&Bs[bj][bc] = wv;
    __syncthreads();
    const float (*Mp)[68] = (j0m < 64) ? aggS : hS;
    const int kb = j0m & 63;
#pragma unroll
    for (int kk = 0; kk < 16; ++kk) {
      float4 b4 = *(const float4*)&Bs[kk][tx * 4];
      float a0 = Mp[tyy * 2 + 0][kb + kk];
      float a1 = Mp[tyy * 2 + 1][kb + kk];
      acc2[0][0] = fmaf(a0, b4.x, acc2[0][0]); acc2[0][1] = fmaf(a0, b4.y, acc2[0][1]);
      acc2[0][2] = fmaf(a0, b4.z, acc2[0][2]); acc2[0][3] = fmaf(a0, b4.w, acc2[0][3]);
      acc2[1][0] = fmaf(a1, b4.x, acc2[1][0]); acc2[1][1] = fmaf(a1, b4.y, acc2[1][1]);
      acc2[1][2] = fmaf(a1, b4.z, acc2[1][2]); acc2[1][3] = fmaf(a1, b4.w, acc2[1][3]);
    }
  }
  __syncthreads();   // done reading aggS/hS

  // ---- dx@Wx + bias, tanh, store h_new into hS ----
  const int ksp = (k < 11) ? k : 10;
#pragma unroll
  for (int r = 0; r < 2; ++r) {
    int iG = i0 + tyy * 2 + r;
    size_t cbase = ((size_t)(b * NN + iG) * NKNOTS + ksp) * 2;
    float dx0 = cb[cbase + 0], dx1 = cb[cbase + 1];
    if (k == 11) {   // frac = 1: der = b + 2c + 3d
      dx0 += 2.f * cc[cbase + 0] + 3.f * cd[cbase + 0];
      dx1 += 2.f * cc[cbase + 1] + 3.f * cd[cbase + 1];
    }
#pragma unroll
    for (int c = 0; c < 4; ++c) {
      int hcol = tx * 4 + c;
      float pre = acc2[r][c] + dx0 * sWx[hcol] + dx1 * sWx[64 + hcol] + sdb[hcol];
      hS[tyy * 2 + r][hcol] = tanhf(pre);   // h_new (STEP=1)
    }
  }
  __syncthreads();

  // ---- write h_new to transposed bf16 hi/lo ring slice (k+2)&3 ----
  {
    const int cl = tid >> 3, ich = (tid & 7) * 8;
    size_t off = ((size_t)((k + 2) & 3) << 20) + (size_t)(c0 + cl) * NN + (i0 + ich);
    ushort8_v H, L;
#pragma unroll
    for (int q = 0; q < 8; ++q) {
      float v = hS[ich + q][cl];
      unsigned short hv = f2bf(v);
      H[q] = hv; L[q] = f2bf(v - bf2f(hv));
    }
    *(ushort8_v*)(SThi + off) = H;
    *(ushort8_v*)(STlo + off) = L;
  }

  // ---- reg head + Huber partial ----
  {
    const int ri = tid >> 3;           // row 0..63
    const int mg = (tid & 7) * 4;      // 4 mids each
    float rpart = 0.f;
#pragma unroll
    for (int m = 0; m < 4; ++m) {
      int mm = mg + m;
      float s = rb1[mm];
#pragma unroll 8
      for (int h = 0; h < 64; ++h) s = fmaf(hS[ri][h], rW1[h * 32 + mm], s);
      rpart += fmaxf(s, 0.f) * rW2[mm];
    }
    rpart += __shfl_down(rpart, 4);
    rpart += __shfl_down(rpart, 2);
    rpart += __shfl_down(rpart, 1);
    if ((tid & 7) == 0) {
      float rv = rpart + rb2[0];
      int iG = i0 + ri;
      size_t tb = ((size_t)(b * NN + iG) * NKNOTS + ksp) * 2;
      float tgt = ca[tb];
      if (k == 11) tgt += cb[tb] + cc[tb] + cd[tb];   // frac=1: a+b+c+d
      float dv = rv - tgt;
      float ad = fabsf(dv);
      redbuf[ri] = (ad < 1.f) ? 0.5f * dv * dv : (ad - 0.5f);
    }
    __syncthreads();
    if (tid < 64) {
      float v = redbuf[tid];
      v += __shfl_down(v, 32);
      v += __shfl_down(v, 16);
      v += __shfl_down(v, 8);
      v += __shfl_down(v, 4);
      v += __shfl_down(v, 2);
      v += __shfl_down(v, 1);
      if (tid == 0) atomicAdd(loss, v);
    }
  }

  // ---- pred head (k == 11 only) ----
  if (k == 11) {
    __syncthreads();
    const int ri = tid >> 3;
    const int mg = (tid & 7) * 4;
#pragma unroll
    for (int m = 0; m < 4; ++m) {
      int mm = mg + m;
      float s = pb1[mm];
#pragma unroll 8
      for (int h = 0; h < 64; ++h) s = fmaf(hS[ri][h], pW1[h * 32 + mm], s);
      aggS[ri][mm] = fmaxf(s, 0.f);
    }
    __syncthreads();
#pragma unroll
    for (int rep = 0; rep < 2; ++rep) {
      int idx = tid + rep * 512;        // 768 = 64 rows x 12 outs
      if (idx < 768) {
        int i_ = idx / 12, o = idx % 12;
        float s = pb2[o];
#pragma unroll
        for (int m = 0; m < 32; ++m) s = fmaf(aggS[i_][m], pW2[m * 12 + o], s);
        out[((size_t)b * NN + (i0 + i_)) * 12 + o] = s;
      }
    }
  }
}

__global__ void finalize_kernel(const float* __restrict__ loss, float* __restrict__ out)
{
  out[196608] = loss[0] * (1.0f / 196608.0f);
}

// -------------------------------------------------------------------------
extern "C" void kernel_launch(void* const* d_in, const int* in_sizes, int n_in,
                              void* d_out, int out_size, void* d_ws, size_t ws_size,
                              hipStream_t stream)
{
  const float* A     = (const float*)d_in[0];
  const float* delay = (const float*)d_in[1];
  const float* ca    = (const float*)d_in[2];
  const float* cb    = (const float*)d_in[3];
  const float* cc    = (const float*)d_in[4];
  const float* cd    = (const float*)d_in[5];
  const float* emb   = (const float*)d_in[6];
  const float* iW1   = (const float*)d_in[7];
  const float* ib1   = (const float*)d_in[8];
  const float* iW2   = (const float*)d_in[9];
  const float* ib2   = (const float*)d_in[10];
  const float* Wm    = (const float*)d_in[11];
  const float* Wsm   = (const float*)d_in[12];
  const float* Wx    = (const float*)d_in[13];
  const float* db    = (const float*)d_in[14];
  const float* rW1   = (const float*)d_in[15];
  const float* rb1   = (const float*)d_in[16];
  const float* rW2   = (const float*)d_in[17];
  const float* rb2   = (const float*)d_in[18];
  const float* pW1   = (const float*)d_in[19];
  const float* pb1   = (const float*)d_in[20];
  const float* pW2   = (const float*)d_in[21];
  const float* pb2   = (const float*)d_in[22];

  char* wsb = (char*)d_ws;
  float* out = (float*)d_out;
  unsigned short* WThi = (unsigned short*)(wsb + WTHI_OFF);
  unsigned short* SThi = (unsigned short*)(wsb + STHI_OFF);
  unsigned short* STlo = (unsigned short*)(wsb + STLO_OFF);
  float* loss = (float*)(wsb + LOSS_OFF);
  float* Z    = (float*)(wsb + Z_OFF);
  float* dinv = (float*)(wsb + DINV_OFF);

  hipMemsetAsync(loss, 0, sizeof(float), stream);
  rowstats_kernel<<<NN, 256, 0, stream>>>(emb, A, Z, dinv);
  build_wt_kernel<<<NN, 256, 0, stream>>>(emb, A, delay, Z, dinv, WThi);
  init_s_kernel<<<NN, 128, 0, stream>>>(ca, iW1, ib1, iW2, ib2, SThi, STlo);
  for (int k = 0; k < 12; ++k) {
    step_kernel<<<256, 512, 0, stream>>>(
        WThi, SThi, STlo, Wm, Wsm, Wx, db, cb, cc, cd, ca,
        rW1, rb1, rW2, rb2, pW1, pb1, pW2, pb2, out, loss, k);
  }
  finalize_kernel<<<1, 1, 0, stream>>>(loss, out);
}

// Round 5
// 494.091 us; speedup vs baseline: 5.2454x; 1.6083x over previous
//
#include <hip/hip_runtime.h>
#include <cstddef>
#include <cstdint>

#define NN 1024
#define BB 16
#define NKNOTS 11

typedef __attribute__((ext_vector_type(8))) short short8_v;
typedef __attribute__((ext_vector_type(4))) float f32x4;
typedef __attribute__((ext_vector_type(8))) unsigned short ushort8_v;

// ---- workspace byte offsets ----
#define WTHI_OFF  ((size_t)0)
#define STHI_OFF  ((size_t)12 << 20)
#define STLO_OFF  ((size_t)20 << 20)
#define LOSS_OFF  ((size_t)28 << 20)
#define Z_OFF     (((size_t)28 << 20) + 64)
#define DINV_OFF  (((size_t)28 << 20) + 64 + 4096)

__device__ __forceinline__ unsigned short f2bf(float x) {
  unsigned int u = __float_as_uint(x);
  return (unsigned short)((u + 0x7FFFu + ((u >> 16) & 1u)) >> 16);
}
__device__ __forceinline__ float bf2f(unsigned short h) {
  return __uint_as_float(((unsigned int)h) << 16);
}
__device__ __forceinline__ void gload16(const void* g, void* l) {
  __builtin_amdgcn_global_load_lds(
      (const __attribute__((address_space(1))) unsigned int*)g,
      (__attribute__((address_space(3))) unsigned int*)l, 16, 0, 0);
}

// -------------------------------------------------------------------------
// Kernel 1: per-row softmax denominator Z[j] and degree rsqrt dinv[j]
// -------------------------------------------------------------------------
__global__ __launch_bounds__(256) void rowstats_kernel(
    const float* __restrict__ emb, const float* __restrict__ A,
    float* __restrict__ Z, float* __restrict__ dinv)
{
  const int j = blockIdx.x;
  const int tid = threadIdx.x;
  __shared__ float ej[64];
  __shared__ float r1[256], r2[256];
  if (tid < 64) ej[tid] = emb[j * 64 + tid];
  __syncthreads();
  float zs = 0.f, as = 0.f;
  for (int i = tid; i < NN; i += 256) {
    const float4* er = (const float4*)(emb + (size_t)i * 64);
    float dot = 0.f;
#pragma unroll
    for (int q = 0; q < 16; ++q) {
      float4 e = er[q];
      dot += e.x * ej[q * 4 + 0] + e.y * ej[q * 4 + 1] +
             e.z * ej[q * 4 + 2] + e.w * ej[q * 4 + 3];
    }
    zs += expf(fmaxf(dot, 0.f));
    as += A[(size_t)j * NN + i];
  }
  r1[tid] = zs; r2[tid] = as;
  __syncthreads();
  for (int s = 128; s > 0; s >>= 1) {
    if (tid < s) { r1[tid] += r1[tid + s]; r2[tid] += r2[tid + s]; }
    __syncthreads();
  }
  if (tid == 0) {
    Z[j] = r1[0];
    dinv[j] = rsqrtf(r2[0] + 1.0f);
  }
}

// -------------------------------------------------------------------------
// Kernel 2: WT[d][i][j] = (dsteps[j][i]==d) ? W[j][i] : 0, bf16
// -------------------------------------------------------------------------
__global__ __launch_bounds__(256) void build_wt_kernel(
    const float* __restrict__ emb, const float* __restrict__ A,
    const float* __restrict__ delay, const float* __restrict__ Z,
    const float* __restrict__ dinv, unsigned short* __restrict__ WThi)
{
  const int i = blockIdx.x;
  const int tid = threadIdx.x;
  __shared__ float ei[64];
  if (tid < 64) ei[tid] = emb[i * 64 + tid];
  __syncthreads();
  const float di = dinv[i];
  for (int j = tid; j < NN; j += 256) {
    const float4* er = (const float4*)(emb + (size_t)j * 64);
    float dot = 0.f;
#pragma unroll
    for (int q = 0; q < 16; ++q) {
      float4 e = er[q];
      dot += e.x * ei[q * 4 + 0] + e.y * ei[q * 4 + 1] +
             e.z * ei[q * 4 + 2] + e.w * ei[q * 4 + 3];
    }
    float sem = expf(fmaxf(dot, 0.f)) / Z[j];
    float aji = A[(size_t)j * NN + i] + ((i == j) ? 1.f : 0.f);
    float ac = sem + dinv[j] * di * aji;
    float w = (ac > 0.001f) ? ac : 0.f;
    float dl = fminf(fmaxf(delay[(size_t)j * NN + i], 0.f), 2.f);
    int dsv = (int)rintf(dl);
#pragma unroll
    for (int d0 = 0; d0 < 3; ++d0) {
      float v = (dsv == d0) ? w : 0.f;
      WThi[((size_t)d0 << 20) + (size_t)i * NN + j] = f2bf(v);
    }
  }
}

// -------------------------------------------------------------------------
// Kernel 3: history init -> transposed bf16 hi/lo ST slices 0,1
// -------------------------------------------------------------------------
__global__ __launch_bounds__(128) void init_s_kernel(
    const float* __restrict__ ca, const float* __restrict__ W1,
    const float* __restrict__ b1, const float* __restrict__ W2,
    const float* __restrict__ b2,
    unsigned short* __restrict__ SThi, unsigned short* __restrict__ STlo)
{
  const int n = blockIdx.x;
  const int tid = threadIdx.x;
  __shared__ float l1[64];
  for (int b = 0; b < BB; ++b) {
    size_t cbase = ((size_t)(b * NN + n) * NKNOTS + 0) * 2;
    float x0 = ca[cbase + 0];
    float x1 = ca[cbase + 1];
    if (tid < 64)
      l1[tid] = fmaxf(x0 * W1[0 * 64 + tid] + x1 * W1[1 * 64 + tid] + b1[tid], 0.f);
    __syncthreads();
    float acc = b2[tid];
#pragma unroll 8
    for (int h = 0; h < 64; ++h) acc = fmaf(l1[h], W2[h * 128 + tid], acc);
    int t = tid >> 6, hh = tid & 63;
    size_t off = ((size_t)t << 20) + (size_t)(b * 64 + hh) * NN + n;
    unsigned short hv = f2bf(acc);
    SThi[off] = hv;
    STlo[off] = f2bf(acc - bf2f(hv));
    __syncthreads();
  }
}

// -------------------------------------------------------------------------
// Kernel 4: one scan step. BK=256 double-buffered 2-phase MFMA GEMM +
//           LDS-staged-weight epilogue. 512 thr, 8 waves = 2wr x 2wc x 2kh.
// -------------------------------------------------------------------------
__global__ __launch_bounds__(512, 1) void step_kernel(
    const unsigned short* __restrict__ WThi,
    unsigned short* __restrict__ SThi, unsigned short* __restrict__ STlo,
    const float* __restrict__ Wm, const float* __restrict__ Wsm,
    const float* __restrict__ Wx, const float* __restrict__ db,
    const float* __restrict__ cb, const float* __restrict__ cc,
    const float* __restrict__ cd, const float* __restrict__ ca,
    const float* __restrict__ rW1, const float* __restrict__ rb1,
    const float* __restrict__ rW2, const float* __restrict__ rb2,
    const float* __restrict__ pW1, const float* __restrict__ pb1,
    const float* __restrict__ pW2, const float* __restrict__ pb2,
    float* __restrict__ out, float* __restrict__ loss, int k)
{
  // GEMM: 2 buffers x 64KB @ 0 / 65536. Buffer: [A 32K][B 32K], row=512B,
  //   XOR-chunk swizzle (chunk ^= row&7 on low 3 bits).
  // Epilogue overlay: aggS[64][68]f @0, hS[64][68]f @17408,
  //   Wgt[128][64]f @34816, rW1 @67584, pW1 @75776.
  __shared__ __align__(16) char smem[131072];
  __shared__ float sWx[128];
  __shared__ float sdb[64];
  __shared__ float redbuf[64];

  const int tid  = threadIdx.x;
  const int lane = tid & 63;
  const int w    = tid >> 6;            // wave 0..7
  const int bid  = blockIdx.x;
  // XCD-aware decode: xcd owns 4 i-tiles x 8 b-tiles
  const int xcd = bid & 7, qq = bid >> 3;
  const int i0 = ((xcd & 3) * 4 + (qq & 3)) * 64;
  const int b  = (xcd >> 2) * 8 + (qq >> 2);
  const int c0 = b * 64;

  const int wr = (w >> 1) & 1, wc = w & 1, kh = w >> 2;
  const int g = lane >> 4, l15 = lane & 15;

  if (tid < 128) sWx[tid] = Wx[tid];
  else if (tid < 192) sdb[tid - 128] = db[tid - 128];

  // fragment byte offsets
  const int rA = (wr * 32 + l15) * 512;
  const int rB = 32768 + (wc * 32 + l15) * 512;
  const int sw = l15 & 7;

  f32x4 acc[2][2];
#pragma unroll
  for (int fr = 0; fr < 2; ++fr)
#pragma unroll
    for (int fc = 0; fc < 2; ++fc)
      acc[fr][fc] = (f32x4){0.f, 0.f, 0.f, 0.f};

  // stage t covers bin d = t>>2, j-cols (t&3)*256; 8 gload16/thread
  auto do_stage = [&](int t) {
    const int d  = t >> 2;
    const int jc = (t & 3) << 8;
    int td = k + 1 - d; if (td < 0) td = 0;
    const unsigned short* Ab = WThi + ((size_t)d << 20) + (size_t)i0 * NN + jc;
    const unsigned short* Bb = SThi + ((size_t)(td & 3) << 20) + (size_t)c0 * NN + jc;
    char* dstb = smem + ((t & 1) << 16);
    const int r0 = (w << 3) + (lane >> 5);
    const int ch = lane & 31;
#pragma unroll
    for (int q = 0; q < 4; ++q) {
      int r = r0 + q * 2;
      int sc = (ch ^ (r & 7)) << 3;          // pre-inverse-swizzled src elems
      int dofs = ((w << 3) + q * 2) * 512 + (lane << 4);
      gload16(Ab + (size_t)r * NN + sc, dstb + dofs);
      gload16(Bb + (size_t)r * NN + sc, dstb + 32768 + dofs);
    }
  };

  do_stage(0);
  asm volatile("s_waitcnt vmcnt(0)" ::: "memory");
  __builtin_amdgcn_s_barrier();

  for (int t = 0; t < 12; ++t) {
    if (t < 11) do_stage(t + 1);           // prefetch into other buffer
    const char* bp = smem + ((t & 1) << 16);
#pragma unroll
    for (int m = 0; m < 4; ++m) {
      const int co = (((kh * 4 + m) * 4 + g) ^ sw) << 4;
      short8_v a0 = *(const short8_v*)(bp + rA + co);
      short8_v a1 = *(const short8_v*)(bp + rA + 8192 + co);
      short8_v b0 = *(const short8_v*)(bp + rB + co);
      short8_v b1 = *(const short8_v*)(bp + rB + 8192 + co);
      acc[0][0] = __builtin_amdgcn_mfma_f32_16x16x32_bf16(a0, b0, acc[0][0], 0, 0, 0);
      acc[0][1] = __builtin_amdgcn_mfma_f32_16x16x32_bf16(a0, b1, acc[0][1], 0, 0, 0);
      acc[1][0] = __builtin_amdgcn_mfma_f32_16x16x32_bf16(a1, b0, acc[1][0], 0, 0, 0);
      acc[1][1] = __builtin_amdgcn_mfma_f32_16x16x32_bf16(a1, b1, acc[1][1], 0, 0, 0);
    }
    __builtin_amdgcn_sched_barrier(0);
    asm volatile("s_waitcnt vmcnt(0)" ::: "memory");  // next-stage landed
    __builtin_amdgcn_s_barrier();
  }

  float (*aggS)[68] = (float (*)[68])smem;
  float (*hS)[68]   = (float (*)[68])(smem + 17408);
  float* Wg   = (float*)(smem + 34816);
  float* rw1l = (float*)(smem + 67584);
  float* pw1l = (float*)(smem + 75776);

  // ---- stage epilogue weights into LDS (overlaps accumulator merge) ----
  {
#pragma unroll
    for (int q = 0; q < 4; ++q) {
      const float* src = (q < 2) ? (Wm + q * 2048) : (Wsm + (q - 2) * 2048);
      gload16(src + tid * 4, smem + 34816 + q * 8192 + tid * 16);
    }
    gload16(rW1 + tid * 4, smem + 67584 + tid * 16);
    gload16(pW1 + tid * 4, smem + 75776 + tid * 16);
  }

  // ---- merge kh halves: kh=0 stores, kh=1 adds ----
  if (kh == 0) {
#pragma unroll
    for (int fr = 0; fr < 2; ++fr)
#pragma unroll
      for (int fc = 0; fc < 2; ++fc)
#pragma unroll
        for (int r = 0; r < 4; ++r)
          aggS[wr * 32 + fr * 16 + g * 4 + r][wc * 32 + fc * 16 + l15] = acc[fr][fc][r];
  }
  __syncthreads();   // also drains weight gloads
  if (kh == 1) {
#pragma unroll
    for (int fr = 0; fr < 2; ++fr)
#pragma unroll
      for (int fc = 0; fc < 2; ++fc)
#pragma unroll
        for (int r = 0; r < 4; ++r)
          aggS[wr * 32 + fr * 16 + g * 4 + r][wc * 32 + fc * 16 + l15] += acc[fr][fc][r];
  }
  // ---- stage h_k tile (fp32 = hi + lo from transposed ST) ----
  {
    const int cl = tid >> 3, ich = (tid & 7) * 8;
    size_t off = ((size_t)((k + 1) & 3) << 20) + (size_t)(c0 + cl) * NN + (i0 + ich);
    ushort8_v h0 = *(const ushort8_v*)(SThi + off);
    ushort8_v l0 = *(const ushort8_v*)(STlo + off);
#pragma unroll
    for (int q = 0; q < 8; ++q)
      hS[ich + q][cl] = bf2f(h0[q]) + bf2f(l0[q]);
  }
  __syncthreads();

  // ---- mini-GEMM: pre_lin = [agg | h_k] (64x128) @ Wgt (128x64), LDS-only --
  const int tx = tid & 15;
  const int tyy = tid >> 4;            // 0..31, two rows each
  float acc2[2][4];
#pragma unroll
  for (int r = 0; r < 2; ++r)
#pragma unroll
    for (int c = 0; c < 4; ++c) acc2[r][c] = 0.f;

#pragma unroll
  for (int half = 0; half < 2; ++half) {
    const float (*Mp)[68] = half ? hS : aggS;
#pragma unroll 4
    for (int kk = 0; kk < 64; ++kk) {
      float4 b4 = *(const float4*)(Wg + (half * 64 + kk) * 64 + tx * 4);
      float a0 = Mp[tyy * 2 + 0][kk];
      float a1 = Mp[tyy * 2 + 1][kk];
      acc2[0][0] = fmaf(a0, b4.x, acc2[0][0]); acc2[0][1] = fmaf(a0, b4.y, acc2[0][1]);
      acc2[0][2] = fmaf(a0, b4.z, acc2[0][2]); acc2[0][3] = fmaf(a0, b4.w, acc2[0][3]);
      acc2[1][0] = fmaf(a1, b4.x, acc2[1][0]); acc2[1][1] = fmaf(a1, b4.y, acc2[1][1]);
      acc2[1][2] = fmaf(a1, b4.z, acc2[1][2]); acc2[1][3] = fmaf(a1, b4.w, acc2[1][3]);
    }
  }
  __syncthreads();   // done reading aggS/hS

  // ---- dx@Wx + bias, tanh, store h_new into hS ----
  const int ksp = (k < 11) ? k : 10;
#pragma unroll
  for (int r = 0; r < 2; ++r) {
    int iG = i0 + tyy * 2 + r;
    size_t cbase = ((size_t)(b * NN + iG) * NKNOTS + ksp) * 2;
    float dx0 = cb[cbase + 0], dx1 = cb[cbase + 1];
    if (k == 11) {   // frac = 1: der = b + 2c + 3d
      dx0 += 2.f * cc[cbase + 0] + 3.f * cd[cbase + 0];
      dx1 += 2.f * cc[cbase + 1] + 3.f * cd[cbase + 1];
    }
#pragma unroll
    for (int c = 0; c < 4; ++c) {
      int hcol = tx * 4 + c;
      float pre = acc2[r][c] + dx0 * sWx[hcol] + dx1 * sWx[64 + hcol] + sdb[hcol];
      hS[tyy * 2 + r][hcol] = tanhf(pre);   // h_new (STEP=1)
    }
  }
  __syncthreads();

  // ---- write h_new to transposed bf16 hi/lo ring slice (k+2)&3 ----
  {
    const int cl = tid >> 3, ich = (tid & 7) * 8;
    size_t off = ((size_t)((k + 2) & 3) << 20) + (size_t)(c0 + cl) * NN + (i0 + ich);
    ushort8_v H, L;
#pragma unroll
    for (int q = 0; q < 8; ++q) {
      float v = hS[ich + q][cl];
      unsigned short hv = f2bf(v);
      H[q] = hv; L[q] = f2bf(v - bf2f(hv));
    }
    *(ushort8_v*)(SThi + off) = H;
    *(ushort8_v*)(STlo + off) = L;
  }

  // ---- reg head + Huber partial (rW1 from LDS) ----
  {
    const int ri = tid >> 3;           // row 0..63
    const int mg = (tid & 7) * 4;      // 4 mids each
    float rpart = 0.f;
#pragma unroll
    for (int m = 0; m < 4; ++m) {
      int mm = mg + m;
      float s = rb1[mm];
#pragma unroll 8
      for (int h = 0; h < 64; ++h) s = fmaf(hS[ri][h], rw1l[h * 32 + mm], s);
      rpart += fmaxf(s, 0.f) * rW2[mm];
    }
    rpart += __shfl_down(rpart, 4);
    rpart += __shfl_down(rpart, 2);
    rpart += __shfl_down(rpart, 1);
    if ((tid & 7) == 0) {
      float rv = rpart + rb2[0];
      int iG = i0 + ri;
      size_t tb = ((size_t)(b * NN + iG) * NKNOTS + ksp) * 2;
      float tgt = ca[tb];
      if (k == 11) tgt += cb[tb] + cc[tb] + cd[tb];   // frac=1: a+b+c+d
      float dv = rv - tgt;
      float ad = fabsf(dv);
      redbuf[ri] = (ad < 1.f) ? 0.5f * dv * dv : (ad - 0.5f);
    }
    __syncthreads();
    if (tid < 64) {
      float v = redbuf[tid];
      v += __shfl_down(v, 32);
      v += __shfl_down(v, 16);
      v += __shfl_down(v, 8);
      v += __shfl_down(v, 4);
      v += __shfl_down(v, 2);
      v += __shfl_down(v, 1);
      if (tid == 0) atomicAdd(loss, v);
    }
  }

  // ---- pred head (k == 11 only; pW1 from LDS) ----
  if (k == 11) {
    __syncthreads();
    const int ri = tid >> 3;
    const int mg = (tid & 7) * 4;
#pragma unroll
    for (int m = 0; m < 4; ++m) {
      int mm = mg + m;
      float s = pb1[mm];
#pragma unroll 8
      for (int h = 0; h < 64; ++h) s = fmaf(hS[ri][h], pw1l[h * 32 + mm], s);
      aggS[ri][mm] = fmaxf(s, 0.f);
    }
    __syncthreads();
#pragma unroll
    for (int rep = 0; rep < 2; ++rep) {
      int idx = tid + rep * 512;        // 768 = 64 rows x 12 outs
      if (idx < 768) {
        int i_ = idx / 12, o = idx % 12;
        float s = pb2[o];
#pragma unroll
        for (int m = 0; m < 32; ++m) s = fmaf(aggS[i_][m], pW2[m * 12 + o], s);
        out[((size_t)b * NN + (i0 + i_)) * 12 + o] = s;
      }
    }
  }
}

__global__ void finalize_kernel(const float* __restrict__ loss, float* __restrict__ out)
{
  out[196608] = loss[0] * (1.0f / 196608.0f);
}

// -------------------------------------------------------------------------
extern "C" void kernel_launch(void* const* d_in, const int* in_sizes, int n_in,
                              void* d_out, int out_size, void* d_ws, size_t ws_size,
                              hipStream_t stream)
{
  const float* A     = (const float*)d_in[0];
  const float* delay = (const float*)d_in[1];
  const float* ca    = (const float*)d_in[2];
  const float* cb    = (const float*)d_in[3];
  const float* cc    = (const float*)d_in[4];
  const float* cd    = (const float*)d_in[5];
  const float* emb   = (const float*)d_in[6];
  const float* iW1   = (const float*)d_in[7];
  const float* ib1   = (const float*)d_in[8];
  const float* iW2   = (const float*)d_in[9];
  const float* ib2   = (const float*)d_in[10];
  const float* Wm    = (const float*)d_in[11];
  const float* Wsm   = (const float*)d_in[12];
  const float* Wx    = (const float*)d_in[13];
  const float* db    = (const float*)d_in[14];
  const float* rW1   = (const float*)d_in[15];
  const float* rb1   = (const float*)d_in[16];
  const float* rW2   = (const float*)d_in[17];
  const float* rb2   = (const float*)d_in[18];
  const float* pW1   = (const float*)d_in[19];
  const float* pb1   = (const float*)d_in[20];
  const float* pW2   = (const float*)d_in[21];
  const float* pb2   = (const float*)d_in[22];

  char* wsb = (char*)d_ws;
  float* out = (float*)d_out;
  unsigned short* WThi = (unsigned short*)(wsb + WTHI_OFF);
  unsigned short* SThi = (unsigned short*)(wsb + STHI_OFF);
  unsigned short* STlo = (unsigned short*)(wsb + STLO_OFF);
  float* loss = (float*)(wsb + LOSS_OFF);
  float* Z    = (float*)(wsb + Z_OFF);
  float* dinv = (float*)(wsb + DINV_OFF);

  hipMemsetAsync(loss, 0, sizeof(float), stream);
  rowstats_kernel<<<NN, 256, 0, stream>>>(emb, A, Z, dinv);
  build_wt_kernel<<<NN, 256, 0, stream>>>(emb, A, delay, Z, dinv, WThi);
  init_s_kernel<<<NN, 128, 0, stream>>>(ca, iW1, ib1, iW2, ib2, SThi, STlo);
  for (int k = 0; k < 12; ++k) {
    step_kernel<<<256, 512, 0, stream>>>(
        WThi, SThi, STlo, Wm, Wsm, Wx, db, cb, cc, cd, ca,
        rW1, rb1, rW2, rb2, pW1, pb1, pW2, pb2, out, loss, k);
  }
  finalize_kernel<<<1, 1, 0, stream>>>(loss, out);
}